// Round 1
// baseline (6874.751 us; speedup 1.0000x reference)
//
#include <hip/hip_runtime.h>
#include <cstddef>
#include <cstdint>

// Round 1: complete fp32 implementation of the NLDGNN forward.
// Dominant cost: connect[10000x10000] @ lin_a_w^T (51.2 GFLOP fp32 vector ALU).
// All other stages are small; quartiles done via exact 3-pass radix select.

constexpr int kN  = 10000;
constexpr int kE  = 320000;
constexpr int kNF = 500;
constexpr int kNH = 256;
constexpr int kC  = 16;
constexpr int kK  = 64;

struct SelState {
  int bin1[2]; int rem1[2];
  int bin2[2]; int rem2[2];
  float thr_base;
};

// ---------------- GEMM: C[M,N2] = A[M,K2] @ B[N2,K2]^T + bias ----------------
// BM=BN=64, BK=16, 256 threads, 4x4 per thread. Bounds-checked everywhere.
__global__ __launch_bounds__(256) void gemm_abT(
    const float* __restrict__ A, const float* __restrict__ B,
    const float* __restrict__ bias, float* __restrict__ Cm,
    int M, int N2, int K2)
{
  __shared__ __align__(16) float As[16][68];
  __shared__ __align__(16) float Bs[16][68];
  const int t  = threadIdx.x;
  const int tx = t & 15, ty = t >> 4;
  const int bm = blockIdx.y * 64, bn = blockIdx.x * 64;
  const int lr = t >> 2;          // 0..63 tile row for loads
  const int lc = (t & 3) << 2;    // 0,4,8,12 col group

  float acc[4][4] = {{0.f,0.f,0.f,0.f},{0.f,0.f,0.f,0.f},
                     {0.f,0.f,0.f,0.f},{0.f,0.f,0.f,0.f}};

  for (int k0 = 0; k0 < K2; k0 += 16) {
    float4 va, vb;
    {
      int gr = bm + lr, gc = k0 + lc;
      if (gr < M && gc + 3 < K2) {
        va = *reinterpret_cast<const float4*>(A + (size_t)gr * K2 + gc);
      } else {
        va.x = (gr < M && gc + 0 < K2) ? A[(size_t)gr * K2 + gc + 0] : 0.f;
        va.y = (gr < M && gc + 1 < K2) ? A[(size_t)gr * K2 + gc + 1] : 0.f;
        va.z = (gr < M && gc + 2 < K2) ? A[(size_t)gr * K2 + gc + 2] : 0.f;
        va.w = (gr < M && gc + 3 < K2) ? A[(size_t)gr * K2 + gc + 3] : 0.f;
      }
    }
    {
      int gr = bn + lr, gc = k0 + lc;
      if (gr < N2 && gc + 3 < K2) {
        vb = *reinterpret_cast<const float4*>(B + (size_t)gr * K2 + gc);
      } else {
        vb.x = (gr < N2 && gc + 0 < K2) ? B[(size_t)gr * K2 + gc + 0] : 0.f;
        vb.y = (gr < N2 && gc + 1 < K2) ? B[(size_t)gr * K2 + gc + 1] : 0.f;
        vb.z = (gr < N2 && gc + 2 < K2) ? B[(size_t)gr * K2 + gc + 2] : 0.f;
        vb.w = (gr < N2 && gc + 3 < K2) ? B[(size_t)gr * K2 + gc + 3] : 0.f;
      }
    }
    As[lc + 0][lr] = va.x; As[lc + 1][lr] = va.y;
    As[lc + 2][lr] = va.z; As[lc + 3][lr] = va.w;
    Bs[lc + 0][lr] = vb.x; Bs[lc + 1][lr] = vb.y;
    Bs[lc + 2][lr] = vb.z; Bs[lc + 3][lr] = vb.w;
    __syncthreads();
#pragma unroll
    for (int kk = 0; kk < 16; kk++) {
      float4 av = *reinterpret_cast<const float4*>(&As[kk][ty << 2]);
      float4 bv = *reinterpret_cast<const float4*>(&Bs[kk][tx << 2]);
      acc[0][0] += av.x * bv.x; acc[0][1] += av.x * bv.y; acc[0][2] += av.x * bv.z; acc[0][3] += av.x * bv.w;
      acc[1][0] += av.y * bv.x; acc[1][1] += av.y * bv.y; acc[1][2] += av.y * bv.z; acc[1][3] += av.y * bv.w;
      acc[2][0] += av.z * bv.x; acc[2][1] += av.z * bv.y; acc[2][2] += av.z * bv.z; acc[2][3] += av.z * bv.w;
      acc[3][0] += av.w * bv.x; acc[3][1] += av.w * bv.y; acc[3][2] += av.w * bv.z; acc[3][3] += av.w * bv.w;
    }
    __syncthreads();
  }
#pragma unroll
  for (int ii = 0; ii < 4; ii++) {
    int r = bm + (ty << 2) + ii;
    if (r >= M) continue;
#pragma unroll
    for (int jj = 0; jj < 4; jj++) {
      int c = bn + (tx << 2) + jj;
      if (c < N2) Cm[(size_t)r * N2 + c] = acc[ii][jj] + (bias ? bias[c] : 0.f);
    }
  }
}

// raw = relu(0.5*h1 + 0.5*xa), float4-vectorized (h1/raw may alias: no restrict)
__global__ void combine_relu4(const float4* h1, const float4* xa, float4* raw, int n4)
{
  int t = blockIdx.x * 256 + threadIdx.x;
  if (t >= n4) return;
  float4 a = h1[t], b = xa[t], r;
  r.x = fmaxf(0.5f * a.x + 0.5f * b.x, 0.f);
  r.y = fmaxf(0.5f * a.y + 0.5f * b.y, 0.f);
  r.z = fmaxf(0.5f * a.z + 0.5f * b.z, 0.f);
  r.w = fmaxf(0.5f * a.w + 0.5f * b.w, 0.f);
  raw[t] = r;
}

// out[i,j] = bias[j] + dot(A[i,:], Bw[j,:]) over K2 (K2 % 4 == 0)
__global__ void gemm_rowdot(const float* __restrict__ A, const float* __restrict__ Bw,
                            const float* __restrict__ bias, float* __restrict__ outm,
                            int M, int N2, int K2)
{
  int t = blockIdx.x * 256 + threadIdx.x;
  if (t >= M * N2) return;
  int i = t / N2, j = t % N2;
  const float4* a = reinterpret_cast<const float4*>(A + (size_t)i * K2);
  const float4* b = reinterpret_cast<const float4*>(Bw + (size_t)j * K2);
  float s = bias ? bias[j] : 0.f;
  int q4 = K2 >> 2;
  for (int q = 0; q < q4; q++) {
    float4 av = a[q], bv = b[q];
    s += av.x * bv.x + av.y * bv.y + av.z * bv.z + av.w * bv.w;
  }
  outm[t] = s;
}

__global__ void argmax16(const float* __restrict__ h, int* __restrict__ y, int n)
{
  int i = blockIdx.x * 256 + threadIdx.x;
  if (i >= n) return;
  const float* r = h + (size_t)i * 16;
  float m = r[0]; int a = 0;
#pragma unroll
  for (int j = 1; j < 16; j++) { float v = r[j]; if (v > m) { m = v; a = j; } }
  y[i] = a;
}

__global__ void scatter_nei(const int* __restrict__ row, const int* __restrict__ col,
                            const float* __restrict__ aw, const int* __restrict__ yhat,
                            float* nei, int E)
{
  int e = blockIdx.x * 256 + threadIdx.x;
  if (e >= E) return;
  atomicAdd(&nei[(size_t)row[e] * 16 + yhat[col[e]]], aw[e]);
}

// normalize nei rows, x_n = relu(nei_n @ lnw^T + lnb), hC = 0.5*h16 + 0.5*x_n
__global__ void norm_xn_h(const float* __restrict__ nei, const float* __restrict__ h16,
                          const float* __restrict__ lnw, const float* __restrict__ lnb,
                          float* __restrict__ hc, int n)
{
  int i = blockIdx.x * 256 + threadIdx.x;
  if (i >= n) return;
  float nv[16]; float s = 0.f;
#pragma unroll
  for (int c = 0; c < 16; c++) { nv[c] = nei[(size_t)i * 16 + c]; s += nv[c]; }
  float inv = (s != 0.f) ? 1.f / s : 0.f;
#pragma unroll
  for (int j = 0; j < 16; j++) {
    float xn = lnb[j];
#pragma unroll
    for (int c = 0; c < 16; c++) xn += (nv[c] * inv) * lnw[j * 16 + c];
    xn = fmaxf(xn, 0.f);
    hc[(size_t)i * 16 + j] = 0.5f * h16[(size_t)i * 16 + j] + 0.5f * xn;
  }
}

__global__ void softmax3(const float* __restrict__ p, float* __restrict__ w)
{
  float a = p[0], b = p[1], c = p[2];
  float m = fmaxf(a, fmaxf(b, c));
  float ea = expf(a - m), eb = expf(b - m), ec = expf(c - m);
  float s = ea + eb + ec;
  w[0] = ea / s; w[1] = eb / s; w[2] = ec / s;
}

__global__ void edge_conf(const int* __restrict__ row, const int* __restrict__ col,
                          const float* __restrict__ lx, const float* __restrict__ attw,
                          const float* __restrict__ ci, const float* __restrict__ wsoft,
                          float* __restrict__ conf, int E)
{
  int e = blockIdx.x * 256 + threadIdx.x;
  if (e >= E) return;
  const float* a = lx + (size_t)row[e] * 16;
  const float* b = lx + (size_t)col[e] * 16;
  float s = 0.f;
#pragma unroll
  for (int c = 0; c < 16; c++) s += fmaxf(a[c] + b[c], 0.f) * attw[c];
  float cf = 1.f / (1.f + expf(-s));
  conf[e] = cf * wsoft[0] + ci[e] * wsoft[1] + ci[(size_t)E + e] * wsoft[2];
}

// out[a*64+b] = sum_i A[i*Ka+a]*B[i*64+b]; grid.x == Ka, 1024 threads
__global__ __launch_bounds__(1024) void cross_gram(
    const float* __restrict__ A, const float* __restrict__ B,
    float* __restrict__ out, int n, int Ka)
{
  const int a  = blockIdx.x;
  const int tb = threadIdx.x & 63;
  const int sl = threadIdx.x >> 6; // 0..15
  float acc = 0.f;
  for (int i = sl; i < n; i += 16)
    acc += A[(size_t)i * Ka + a] * B[(size_t)i * 64 + tb];
  __shared__ float red[1024];
  red[threadIdx.x] = acc;
  __syncthreads();
  if (threadIdx.x < 64) {
    float s = 0.f;
#pragma unroll
    for (int q = 0; q < 16; q++) s += red[tb + q * 64];
    out[a * 64 + tb] = s;
  }
}

// Gauss-Jordan inverse of (alpha*G + beta*I), 64x64, single block of 256
__global__ __launch_bounds__(256) void inverse64(
    const float* __restrict__ G, float* __restrict__ Gi, float alpha, float beta)
{
  __shared__ float A[64][129];
  __shared__ float pv[64];
  __shared__ int   pi[64];
  const int t = threadIdx.x;
  for (int q = t; q < 64 * 64; q += 256) {
    int r = q >> 6, c = q & 63;
    A[r][c] = alpha * G[q] + ((r == c) ? beta : 0.f);
    A[r][64 + c] = (r == c) ? 1.f : 0.f;
  }
  __syncthreads();
  for (int k = 0; k < 64; k++) {
    if (t < 64) { pv[t] = (t >= k) ? fabsf(A[t][k]) : -1.f; pi[t] = t; }
    __syncthreads();
    for (int s = 32; s > 0; s >>= 1) {
      if (t < s) { if (pv[t + s] > pv[t]) { pv[t] = pv[t + s]; pi[t] = pi[t + s]; } }
      __syncthreads();
    }
    int p = pi[0];
    if (p != k) {
      for (int c = t; c < 128; c += 256) { float tmp = A[k][c]; A[k][c] = A[p][c]; A[p][c] = tmp; }
    }
    __syncthreads();
    float pinv = 1.f / A[k][k];
    for (int c = t; c < 128; c += 256) A[k][c] *= pinv;
    __syncthreads();
    int i = t & 63, g = t >> 6;
    float f = A[i][k];
    __syncthreads();
    if (i != k) {
#pragma unroll
      for (int cc = 0; cc < 32; cc++) {
        int c = g * 32 + cc;
        A[i][c] -= f * A[k][c];
      }
    }
    __syncthreads();
  }
  for (int q = t; q < 64 * 64; q += 256) Gi[q] = A[q >> 6][64 + (q & 63)];
}

// out[oidx[e],:] += val[e]*Msrc[sidx[e],:]  (K=64, 16 threads/edge, float4)
__global__ void spmm64(const float* __restrict__ val, const int* __restrict__ oidx,
                       const int* __restrict__ sidx, const float* __restrict__ Msrc,
                       float* outm, int E)
{
  int t = blockIdx.x * 256 + threadIdx.x;
  int e = t >> 4;
  if (e >= E) return;
  float v = val[e];
  if (v == 0.f) return;
  int f = (t & 15) << 2;
  const float4 m = *reinterpret_cast<const float4*>(Msrc + (size_t)sidx[e] * 64 + f);
  float* o = outm + (size_t)oidx[e] * 64 + f;
  atomicAdd(o + 0, v * m.x);
  atomicAdd(o + 1, v * m.y);
  atomicAdd(o + 2, v * m.z);
  atomicAdd(o + 3, v * m.w);
}

// score[e] = ew[e] - dot64(Ma[row[e]], Mb[col[e]])
__global__ void edge_score(const float* __restrict__ ew, const int* __restrict__ row,
                           const int* __restrict__ col, const float* __restrict__ Ma,
                           const float* __restrict__ Mb, float* __restrict__ score, int E)
{
  int e = blockIdx.x * 256 + threadIdx.x;
  if (e >= E) return;
  const float4* a = reinterpret_cast<const float4*>(Ma + (size_t)row[e] * 64);
  const float4* b = reinterpret_cast<const float4*>(Mb + (size_t)col[e] * 64);
  float s = 0.f;
#pragma unroll
  for (int q = 0; q < 16; q++) {
    float4 av = a[q], bv = b[q];
    s += av.x * bv.x + av.y * bv.y + av.z * bv.z + av.w * bv.w;
  }
  score[e] = ew[e] - s;
}

// ---- exact order-statistic selection on S = score^2 (non-negative floats) ----
__global__ void hist_pass1(const float* __restrict__ score, int* __restrict__ h, int E)
{
  int e = blockIdx.x * 256 + threadIdx.x;
  if (e >= E) return;
  float sc = score[e];
  unsigned u = __float_as_uint(sc * sc);
  atomicAdd(&h[u >> 20], 1);
}

__global__ void hist_pass2(const float* __restrict__ score, const SelState* __restrict__ sel,
                           int* __restrict__ h2a, int* __restrict__ h2b, int E)
{
  int e = blockIdx.x * 256 + threadIdx.x;
  if (e >= E) return;
  float sc = score[e];
  unsigned u = __float_as_uint(sc * sc);
  int top = (int)(u >> 20);
  if (top == sel->bin1[0]) atomicAdd(&h2a[(u >> 8) & 0xFFF], 1);
  if (top == sel->bin1[1]) atomicAdd(&h2b[(u >> 8) & 0xFFF], 1);
}

__global__ void hist_pass3(const float* __restrict__ score, const SelState* __restrict__ sel,
                           int* __restrict__ h3a, int* __restrict__ h3b, int E)
{
  int e = blockIdx.x * 256 + threadIdx.x;
  if (e >= E) return;
  float sc = score[e];
  unsigned u = __float_as_uint(sc * sc);
  int pre = (int)(u >> 8);
  if (pre == ((sel->bin1[0] << 12) | sel->bin2[0])) atomicAdd(&h3a[u & 255], 1);
  if (pre == ((sel->bin1[1] << 12) | sel->bin2[1])) atomicAdd(&h3b[u & 255], 1);
}

// single block, 256 threads. stage 1: ranks {E/4, 3E/4}; 2: rem1; 3: rem2 -> thr
__global__ __launch_bounds__(256) void select_scan(
    const int* __restrict__ h0, const int* __restrict__ h1,
    int nbins, int stage, SelState* sel)
{
  const int t = threadIdx.x;
  __shared__ int part[256];
  __shared__ int foundBin[2];
  __shared__ float qsh[2];
  const int per = nbins / 256;
  for (int tgt = 0; tgt < 2; tgt++) {
    const int* H = tgt ? h1 : h0;
    int R;
    if (stage == 1)      R = tgt ? (3 * kE / 4) : (kE / 4);
    else if (stage == 2) R = sel->rem1[tgt];
    else                 R = sel->rem2[tgt];
    int lsum = 0;
    for (int b = 0; b < per; b++) lsum += H[t * per + b];
    part[t] = lsum;
    __syncthreads();
    for (int off = 1; off < 256; off <<= 1) {
      int v = part[t];
      int u = (t >= off) ? part[t - off] : 0;
      __syncthreads();
      part[t] = v + u;
      __syncthreads();
    }
    int cum = part[t] - lsum;  // exclusive prefix before this thread's chunk
    int fb = -1, fr = 0;
    for (int b = 0; b < per; b++) {
      int c = H[t * per + b];
      if (R >= cum && R < cum + c) { fb = t * per + b; fr = R - cum; }
      cum += c;
    }
    if (fb >= 0) {
      foundBin[tgt] = fb;
      if (stage == 1) { sel->bin1[tgt] = fb; sel->rem1[tgt] = fr; }
      else if (stage == 2) { sel->bin2[tgt] = fb; sel->rem2[tgt] = fr; }
    }
    __syncthreads();
    if (stage == 3 && t == 0) {
      unsigned u = ((unsigned)sel->bin1[tgt] << 20) | ((unsigned)sel->bin2[tgt] << 8)
                 | (unsigned)foundBin[tgt];
      qsh[tgt] = __uint_as_float(u);
    }
    __syncthreads();
  }
  if (stage == 3 && t == 0) {
    float q1 = qsh[0], q3 = qsh[1];
    sel->thr_base = q3 + 1.5f * (q3 - q1);
  }
}

__global__ void mask_SS(const float* __restrict__ score, const float* __restrict__ conf,
                        const SelState* __restrict__ sel, const float* __restrict__ bp,
                        float* __restrict__ SS, int E)
{
  int e = blockIdx.x * 256 + threadIdx.x;
  if (e >= E) return;
  float sc = score[e];
  float thr = sel->thr_base * conf[e];
  SS[e] = (sc * sc < thr) ? (sc + bp[0]) : 0.f;
}

// T[i,k] = sum_j X[i,j]*G[j,k] + EPS * sum_c hc[i,c]*hTX[c,k]
__global__ void base_temp(const float* __restrict__ X, const float* __restrict__ G,
                          const float* __restrict__ hc, const float* __restrict__ hTX,
                          float* __restrict__ T, int n)
{
  int t = blockIdx.x * 256 + threadIdx.x;
  if (t >= n * 64) return;
  int i = t >> 6, k = t & 63;
  const float* xi = X + (size_t)i * 64;
  float s = 0.f;
#pragma unroll 8
  for (int j = 0; j < 64; j++) s += xi[j] * G[j * 64 + k];
  float s2 = 0.f;
#pragma unroll
  for (int c = 0; c < 16; c++) s2 += hc[(size_t)i * 16 + c] * hTX[c * 64 + k];
  T[t] = s + 0.1f * s2;
}

// Out[i,k] = sum_j T[i,j]*Gi[j,k]
__global__ void mul_right64(const float* __restrict__ T, const float* __restrict__ Gi,
                            float* __restrict__ Out, int n)
{
  int t = blockIdx.x * 256 + threadIdx.x;
  if (t >= n * 64) return;
  int i = t >> 6, k = t & 63;
  const float* ti = T + (size_t)i * 64;
  float s = 0.f;
#pragma unroll 8
  for (int j = 0; j < 64; j++) s += ti[j] * Gi[j * 64 + k];
  Out[t] = s;
}

// out = (0.9 * (U @ hTV^T) + 0.1 * hC) @ W
__global__ __launch_bounds__(256) void final_out(
    const float* __restrict__ Um, const float* __restrict__ hTV,
    const float* __restrict__ hc, const float* __restrict__ Wm,
    float* __restrict__ out, int n)
{
  __shared__ float sh[1024];
  __shared__ float sW[256];
  for (int q = threadIdx.x; q < 1024; q += 256) sh[q] = hTV[q];
  sW[threadIdx.x] = Wm[threadIdx.x & 255];
  __syncthreads();
  int i = blockIdx.x * 256 + threadIdx.x;
  if (i >= n) return;
  const float* u = Um + (size_t)i * 64;
  float pre[16];
#pragma unroll
  for (int c = 0; c < 16; c++) {
    float s = 0.f;
#pragma unroll
    for (int k = 0; k < 64; k++) s += u[k] * sh[c * 64 + k];
    pre[c] = 0.9f * s + 0.1f * hc[(size_t)i * 16 + c];
  }
#pragma unroll
  for (int j = 0; j < 16; j++) {
    float o = 0.f;
#pragma unroll
    for (int c = 0; c < 16; c++) o += pre[c] * sW[c * 16 + j];
    out[(size_t)i * 16 + j] = o;
  }
}

extern "C" void kernel_launch(void* const* d_in, const int* in_sizes, int n_in,
                              void* d_out, int out_size, void* d_ws, size_t ws_size,
                              hipStream_t stream)
{
  const float* x       = (const float*)d_in[0];
  const int*   eidx    = (const int*)d_in[1];
  const float* ew      = (const float*)d_in[2];
  const float* aw      = (const float*)d_in[3];
  const float* connect = (const float*)d_in[4];
  const float* ci      = (const float*)d_in[5];
  const float* lin1_w  = (const float*)d_in[6];
  const float* lin1_b  = (const float*)d_in[7];
  const float* lin2_w  = (const float*)d_in[8];
  const float* lin2_b  = (const float*)d_in[9];
  const float* lin_a_w = (const float*)d_in[10];
  const float* lin_a_b = (const float*)d_in[11];
  const float* lin_n_w = (const float*)d_in[12];
  const float* lin_n_b = (const float*)d_in[13];
  const float* left_w  = (const float*)d_in[14];
  const float* att_w   = (const float*)d_in[15];
  const float* v_w     = (const float*)d_in[16];
  const float* v_b     = (const float*)d_in[17];
  const float* Wm      = (const float*)d_in[18];
  const float* conf_p  = (const float*)d_in[19];
  const float* b_param = (const float*)d_in[20];
  const int* row = eidx;
  const int* col = eidx + kE;
  float* out = (float*)d_out;

  // -------- workspace layout (~35 MB) --------
  char* base = (char*)d_ws;
  size_t off = 0;
  auto alloc = [&](size_t bytes) -> void* {
    void* p = base + off;
    off += bytes;
    off = (off + 255) & ~(size_t)255;
    return p;
  };
  float* xa    = (float*)alloc((size_t)kN * kNH * 4);
  float* raw   = (float*)alloc((size_t)kN * kNH * 4);
  float* h16   = (float*)alloc((size_t)kN * kC * 4);
  float* hC    = (float*)alloc((size_t)kN * kC * 4);
  float* nei   = (float*)alloc((size_t)kN * kC * 4);
  float* lx    = (float*)alloc((size_t)kN * kC * 4);
  int*   yhat  = (int*)alloc((size_t)kN * 4);
  float* conf  = (float*)alloc((size_t)kE * 4);
  float* V     = (float*)alloc((size_t)kN * kK * 4);
  float* U     = (float*)alloc((size_t)kN * kK * 4);
  float* T     = (float*)alloc((size_t)kN * kK * 4);
  float* score = (float*)alloc((size_t)kE * 4);
  float* SS    = (float*)alloc((size_t)kE * 4);
  float* G     = (float*)alloc(64 * 64 * 4);
  float* Gi    = (float*)alloc(64 * 64 * 4);
  float* hTX   = (float*)alloc(kC * kK * 4);
  int* hist1   = (int*)alloc(4096 * 4);
  int* h2a     = (int*)alloc(4096 * 4);
  int* h2b     = (int*)alloc(4096 * 4);
  int* h3a     = (int*)alloc(256 * 4);
  int* h3b     = (int*)alloc(256 * 4);
  SelState* sel = (SelState*)alloc(sizeof(SelState));
  float* wsoft = (float*)alloc(4 * 4);
  size_t histSpan = (size_t)((char*)(h3b + 256) - (char*)hist1);

  const int eg = (kE + 255) / 256;        // edge grid
  const int nkg = (kN * kK + 255) / 256;  // N*K grid
  const int spg = (kE * 16 + 255) / 256;  // spmm grid

  // x_a = connect @ lin_a_w^T + lin_a_b   (the big one)
  {
    dim3 g(kNH / 64, (kN + 63) / 64);
    gemm_abT<<<g, 256, 0, stream>>>(connect, lin_a_w, lin_a_b, xa, kN, kNH, kN);
  }
  // h1 = x @ lin1_w^T + lin1_b (into raw)
  {
    dim3 g(kNH / 64, (kN + 63) / 64);
    gemm_abT<<<g, 256, 0, stream>>>(x, lin1_w, lin1_b, raw, kN, kNH, kNF);
  }
  // raw = relu(0.5*h1 + 0.5*xa)
  combine_relu4<<<(kN * kNH / 4 + 255) / 256, 256, 0, stream>>>(
      (const float4*)raw, (const float4*)xa, (float4*)raw, kN * kNH / 4);
  // h16 = raw @ lin2_w^T + lin2_b
  gemm_rowdot<<<(kN * kC + 255) / 256, 256, 0, stream>>>(raw, lin2_w, lin2_b, h16, kN, kC, kNH);
  // y_hat = argmax(h16)
  argmax16<<<(kN + 255) / 256, 256, 0, stream>>>(h16, yhat, kN);
  // nei = row-normalized scatter of adj_weight onto one-hot labels
  hipMemsetAsync(nei, 0, (size_t)kN * kC * 4, stream);
  scatter_nei<<<eg, 256, 0, stream>>>(row, col, aw, yhat, nei, kE);
  // hC = 0.5*h16 + 0.5*relu(nei_n @ lin_n^T + b)   (== init == h)
  norm_xn_h<<<(kN + 255) / 256, 256, 0, stream>>>(nei, h16, lin_n_w, lin_n_b, hC, kN);
  // lx = hC @ left_w^T
  gemm_rowdot<<<(kN * kC + 255) / 256, 256, 0, stream>>>(hC, left_w, nullptr, lx, kN, kC, kC);
  // conf per edge
  softmax3<<<1, 1, 0, stream>>>(conf_p, wsoft);
  edge_conf<<<eg, 256, 0, stream>>>(row, col, lx, att_w, ci, wsoft, conf, kE);
  // V = raw @ v_w^T + v_b
  gemm_rowdot<<<(kN * kK + 255) / 256, 256, 0, stream>>>(raw, v_w, v_b, V, kN, kK, kNH);
  // U = spmm(adj,row,V[col]) @ inv(V^T V)
  cross_gram<<<64, 1024, 0, stream>>>(V, V, G, kN, 64);
  inverse64<<<1, 256, 0, stream>>>(G, Gi, 1.0f, 0.0f);
  hipMemsetAsync(T, 0, (size_t)kN * kK * 4, stream);
  spmm64<<<spg, 256, 0, stream>>>(aw, row, col, V, T, kE);
  mul_right64<<<nkg, 256, 0, stream>>>(T, Gi, U, kN);

  for (int j = 0; j < 4; j++) {
    bool upd_u = ((j & 1) == 0);
    const float* Ma = upd_u ? U : V;  // gathered by row
    const float* Mb = upd_u ? V : U;  // gathered by col
    edge_score<<<eg, 256, 0, stream>>>(ew, row, col, Ma, Mb, score, kE);
    // exact quartile select on score^2
    hipMemsetAsync(hist1, 0, histSpan, stream);
    hist_pass1<<<eg, 256, 0, stream>>>(score, hist1, kE);
    select_scan<<<1, 256, 0, stream>>>(hist1, hist1, 4096, 1, sel);
    hist_pass2<<<eg, 256, 0, stream>>>(score, sel, h2a, h2b, kE);
    select_scan<<<1, 256, 0, stream>>>(h2a, h2b, 4096, 2, sel);
    hist_pass3<<<eg, 256, 0, stream>>>(score, sel, h3a, h3b, kE);
    select_scan<<<1, 256, 0, stream>>>(h3a, h3b, 256, 3, sel);
    mask_SS<<<eg, 256, 0, stream>>>(score, conf, sel, b_param, SS, kE);
    // gram + h^T(other) + inverse
    const float* Xcur = upd_u ? U : V;
    const float* Moth = upd_u ? V : U;
    cross_gram<<<64, 1024, 0, stream>>>(Moth, Moth, G, kN, 64);
    cross_gram<<<16, 1024, 0, stream>>>(hC, Moth, hTX, kN, 16);
    inverse64<<<1, 256, 0, stream>>>(G, Gi, 1.1f, 1.0f);
    // temp = base + spmm
    base_temp<<<nkg, 256, 0, stream>>>(Xcur, G, hC, hTX, T, kN);
    if (upd_u) spmm64<<<spg, 256, 0, stream>>>(SS, row, col, V, T, kE);
    else       spmm64<<<spg, 256, 0, stream>>>(SS, col, row, U, T, kE);
    mul_right64<<<nkg, 256, 0, stream>>>(T, Gi, upd_u ? U : V, kN);
  }

  // out = (0.9 * U @ (h^T V)^T + 0.1 * hC) @ W
  cross_gram<<<16, 1024, 0, stream>>>(hC, V, hTX, kN, 16);
  final_out<<<(kN + 255) / 256, 256, 0, stream>>>(U, hTX, hC, Wm, out, kN);
}

// Round 4
// 5043.156 us; speedup vs baseline: 1.3632x; 1.3632x over previous
//
#include <hip/hip_runtime.h>
#include <cstddef>
#include <cstdint>

// Round 4: round-3 content, compile fix only (removed the after-use helper).
//  (1) CSR count/fill zeroing span computed by pointer-diff (R2 core dump fix).
//  (2) spmm_gather grid sized to rows/4 blocks.

constexpr int kN  = 10000;
constexpr int kE  = 320000;
constexpr int kNH = 256;
constexpr int kC  = 16;
constexpr int kK  = 64;

struct SelState {
  int bin1[2]; int rem1[2];
  int bin2[2]; int rem2[2];
  float thr_base;
};

typedef short bf16x8 __attribute__((ext_vector_type(8)));
typedef float f32x4 __attribute__((ext_vector_type(4)));

__device__ __forceinline__ ushort f2bf(float x) {
  unsigned u = __float_as_uint(x);
  unsigned r = (u + 0x7fffu + ((u >> 16) & 1u)) >> 16;   // RNE
  return (ushort)r;
}
__device__ __forceinline__ float bf2f(ushort h) {
  return __uint_as_float((unsigned)h << 16);
}

// ================= split-bf16 MFMA GEMM: C[10000,256] = A[10000,K]@B[256,K]^T + bias
// grid(125, 2), 256 threads. BM=80, BN=128, BK=64. 3-term split (hi*hi+lo*hi+hi*lo).
__global__ __launch_bounds__(256) void gemm_sbf16(
    const float* __restrict__ A, const float* __restrict__ B,
    const float* __restrict__ bias, float* __restrict__ C, int Kd)
{
  __shared__ __align__(16) ushort Ah[80 * 72];
  __shared__ __align__(16) ushort Al[80 * 72];
  __shared__ __align__(16) ushort Bh[128 * 72];
  __shared__ __align__(16) ushort Bl[128 * 72];
  const int t = threadIdx.x;
  const int bm = blockIdx.x * 80;
  const int bn = blockIdx.y * 128;
  const int lane = t & 63, w = t >> 6;
  const int l15 = lane & 15, lhi8 = (lane >> 4) * 8;

  f32x4 acc[5][2] = {};
  const int nk = (Kd + 63) / 64;
  for (int kt = 0; kt < nk; kt++) {
    const int k0 = kt * 64;
#pragma unroll
    for (int i2 = 0; i2 < 5; i2++) {
      int idx = t + i2 * 256;
      int r = idx >> 4, kc = (idx & 15) << 2;
      float4 v = make_float4(0.f, 0.f, 0.f, 0.f);
      if (k0 + kc < Kd)
        v = *reinterpret_cast<const float4*>(A + (size_t)(bm + r) * Kd + k0 + kc);
      ushort4 hi, lo;
      hi.x = f2bf(v.x); lo.x = f2bf(v.x - bf2f(hi.x));
      hi.y = f2bf(v.y); lo.y = f2bf(v.y - bf2f(hi.y));
      hi.z = f2bf(v.z); lo.z = f2bf(v.z - bf2f(hi.z));
      hi.w = f2bf(v.w); lo.w = f2bf(v.w - bf2f(hi.w));
      *reinterpret_cast<ushort4*>(&Ah[r * 72 + kc]) = hi;
      *reinterpret_cast<ushort4*>(&Al[r * 72 + kc]) = lo;
    }
#pragma unroll
    for (int i2 = 0; i2 < 8; i2++) {
      int idx = t + i2 * 256;
      int r = idx >> 4, kc = (idx & 15) << 2;
      float4 v = make_float4(0.f, 0.f, 0.f, 0.f);
      if (k0 + kc < Kd)
        v = *reinterpret_cast<const float4*>(B + (size_t)(bn + r) * Kd + k0 + kc);
      ushort4 hi, lo;
      hi.x = f2bf(v.x); lo.x = f2bf(v.x - bf2f(hi.x));
      hi.y = f2bf(v.y); lo.y = f2bf(v.y - bf2f(hi.y));
      hi.z = f2bf(v.z); lo.z = f2bf(v.z - bf2f(hi.z));
      hi.w = f2bf(v.w); lo.w = f2bf(v.w - bf2f(hi.w));
      *reinterpret_cast<ushort4*>(&Bh[r * 72 + kc]) = hi;
      *reinterpret_cast<ushort4*>(&Bl[r * 72 + kc]) = lo;
    }
    __syncthreads();
#pragma unroll
    for (int kh = 0; kh < 2; kh++) {
      const int kk = kh * 32;
      bf16x8 bhh[2], bll[2];
#pragma unroll
      for (int nb = 0; nb < 2; nb++) {
        int rr = w * 32 + nb * 16 + l15;
        bhh[nb] = *reinterpret_cast<const bf16x8*>(&Bh[rr * 72 + kk + lhi8]);
        bll[nb] = *reinterpret_cast<const bf16x8*>(&Bl[rr * 72 + kk + lhi8]);
      }
#pragma unroll
      for (int rb = 0; rb < 5; rb++) {
        int rr = rb * 16 + l15;
        bf16x8 ahh = *reinterpret_cast<const bf16x8*>(&Ah[rr * 72 + kk + lhi8]);
        bf16x8 all = *reinterpret_cast<const bf16x8*>(&Al[rr * 72 + kk + lhi8]);
#pragma unroll
        for (int nb = 0; nb < 2; nb++) {
          acc[rb][nb] = __builtin_amdgcn_mfma_f32_16x16x32_bf16(ahh, bhh[nb], acc[rb][nb], 0, 0, 0);
          acc[rb][nb] = __builtin_amdgcn_mfma_f32_16x16x32_bf16(all, bhh[nb], acc[rb][nb], 0, 0, 0);
          acc[rb][nb] = __builtin_amdgcn_mfma_f32_16x16x32_bf16(ahh, bll[nb], acc[rb][nb], 0, 0, 0);
        }
      }
    }
    __syncthreads();
  }
#pragma unroll
  for (int rb = 0; rb < 5; rb++) {
#pragma unroll
    for (int nb = 0; nb < 2; nb++) {
      int colg = bn + w * 32 + nb * 16 + l15;
      float bv = bias ? bias[colg] : 0.f;
#pragma unroll
      for (int j = 0; j < 4; j++) {
        int rowg = bm + rb * 16 + (lane >> 4) * 4 + j;
        C[(size_t)rowg * 256 + colg] = acc[rb][nb][j] + bv;
      }
    }
  }
}

// raw = relu(0.5*h1 + 0.5*xa) (may alias h1/raw)
__global__ void combine_relu4(const float4* h1, const float4* xa, float4* raw, int n4)
{
  int t = blockIdx.x * 256 + threadIdx.x;
  if (t >= n4) return;
  float4 a = h1[t], b = xa[t], r;
  r.x = fmaxf(0.5f * a.x + 0.5f * b.x, 0.f);
  r.y = fmaxf(0.5f * a.y + 0.5f * b.y, 0.f);
  r.z = fmaxf(0.5f * a.z + 0.5f * b.z, 0.f);
  r.w = fmaxf(0.5f * a.w + 0.5f * b.w, 0.f);
  raw[t] = r;
}

__global__ void gemm_rowdot(const float* __restrict__ A, const float* __restrict__ Bw,
                            const float* __restrict__ bias, float* __restrict__ outm,
                            int M, int N2, int K2)
{
  int t = blockIdx.x * 256 + threadIdx.x;
  if (t >= M * N2) return;
  int i = t / N2, j = t % N2;
  const float4* a = reinterpret_cast<const float4*>(A + (size_t)i * K2);
  const float4* b = reinterpret_cast<const float4*>(Bw + (size_t)j * K2);
  float s = bias ? bias[j] : 0.f;
  int q4 = K2 >> 2;
  for (int q = 0; q < q4; q++) {
    float4 av = a[q], bv = b[q];
    s += av.x * bv.x + av.y * bv.y + av.z * bv.z + av.w * bv.w;
  }
  outm[t] = s;
}

__global__ void argmax16(const float* __restrict__ h, int* __restrict__ y, int n)
{
  int i = blockIdx.x * 256 + threadIdx.x;
  if (i >= n) return;
  const float* r = h + (size_t)i * 16;
  float m = r[0]; int a = 0;
#pragma unroll
  for (int j = 1; j < 16; j++) { float v = r[j]; if (v > m) { m = v; a = j; } }
  y[i] = a;
}

__global__ void scatter_nei(const int* __restrict__ row, const int* __restrict__ col,
                            const float* __restrict__ aw, const int* __restrict__ yhat,
                            float* nei, int E)
{
  int e = blockIdx.x * 256 + threadIdx.x;
  if (e >= E) return;
  atomicAdd(&nei[(size_t)row[e] * 16 + yhat[col[e]]], aw[e]);
}

__global__ void norm_xn_h(const float* __restrict__ nei, const float* __restrict__ h16,
                          const float* __restrict__ lnw, const float* __restrict__ lnb,
                          float* __restrict__ hc, int n)
{
  int i = blockIdx.x * 256 + threadIdx.x;
  if (i >= n) return;
  float nv[16]; float s = 0.f;
#pragma unroll
  for (int c = 0; c < 16; c++) { nv[c] = nei[(size_t)i * 16 + c]; s += nv[c]; }
  float inv = (s != 0.f) ? 1.f / s : 0.f;
#pragma unroll
  for (int j = 0; j < 16; j++) {
    float xn = lnb[j];
#pragma unroll
    for (int c = 0; c < 16; c++) xn += (nv[c] * inv) * lnw[j * 16 + c];
    xn = fmaxf(xn, 0.f);
    hc[(size_t)i * 16 + j] = 0.5f * h16[(size_t)i * 16 + j] + 0.5f * xn;
  }
}

__global__ void softmax3(const float* __restrict__ p, float* __restrict__ w)
{
  float a = p[0], b = p[1], c = p[2];
  float m = fmaxf(a, fmaxf(b, c));
  float ea = expf(a - m), eb = expf(b - m), ec = expf(c - m);
  float s = ea + eb + ec;
  w[0] = ea / s; w[1] = eb / s; w[2] = ec / s;
}

__global__ void edge_conf(const int* __restrict__ row, const int* __restrict__ col,
                          const float* __restrict__ lx, const float* __restrict__ attw,
                          const float* __restrict__ ci, const float* __restrict__ wsoft,
                          float* __restrict__ conf, int E)
{
  int e = blockIdx.x * 256 + threadIdx.x;
  if (e >= E) return;
  const float* a = lx + (size_t)row[e] * 16;
  const float* b = lx + (size_t)col[e] * 16;
  float s = 0.f;
#pragma unroll
  for (int c = 0; c < 16; c++) s += fmaxf(a[c] + b[c], 0.f) * attw[c];
  float cf = 1.f / (1.f + expf(-s));
  conf[e] = cf * wsoft[0] + ci[e] * wsoft[1] + ci[(size_t)E + e] * wsoft[2];
}

// ---------------- CSR build ----------------
__global__ void csr_count(const int* __restrict__ row, const int* __restrict__ col,
                          int* cntR, int* cntC, int E)
{
  int e = blockIdx.x * 256 + threadIdx.x;
  if (e >= E) return;
  atomicAdd(&cntR[row[e]], 1);
  atomicAdd(&cntC[col[e]], 1);
}

__global__ __launch_bounds__(1024) void scan2(const int* __restrict__ cntR, const int* __restrict__ cntC,
                                              int* __restrict__ startR, int* __restrict__ startC, int n)
{
  __shared__ int part[1024];
  const int t = threadIdx.x;
  for (int pass = 0; pass < 2; ++pass) {
    const int* cnt = pass ? cntC : cntR;
    int* start = pass ? startC : startR;
    int base = t * 10;
    int loc[10]; int s = 0;
#pragma unroll
    for (int q = 0; q < 10; q++) { int idx = base + q; int v = (idx < n) ? cnt[idx] : 0; loc[q] = v; s += v; }
    part[t] = s;
    __syncthreads();
    for (int off = 1; off < 1024; off <<= 1) {
      int v = part[t];
      int u = (t >= off) ? part[t - off] : 0;
      __syncthreads();
      part[t] = v + u;
      __syncthreads();
    }
    int run = part[t] - s;
#pragma unroll
    for (int q = 0; q < 10; q++) { int idx = base + q; if (idx < n) start[idx] = run; run += loc[q]; }
    if (t == 1023) start[n] = part[1023];
    __syncthreads();
  }
}

__global__ void csr_fill(const int* __restrict__ row, const int* __restrict__ col,
                         const int* __restrict__ startR, const int* __restrict__ startC,
                         int* fillR, int* fillC, int* eR, int* eC, int E)
{
  int e = blockIdx.x * 256 + threadIdx.x;
  if (e >= E) return;
  int r = row[e]; eR[startR[r] + atomicAdd(&fillR[r], 1)] = e;
  int c = col[e]; eC[startC[c] + atomicAdd(&fillC[c], 1)] = e;
}

// T[i,:] += sum over edges of segment i: vals[e] * Msrc[other[e],:]   (wave per row)
__global__ void spmm_gather(const float* __restrict__ vals, const int* __restrict__ start,
                            const int* __restrict__ eids, const int* __restrict__ other,
                            const float* __restrict__ Msrc, float* __restrict__ T, int n)
{
  int wid = blockIdx.x * 4 + (threadIdx.x >> 6);
  int lane = threadIdx.x & 63;
  if (wid >= n) return;
  int p = start[wid], pend = start[wid + 1];
  float acc = 0.f;
  for (; p < pend; ++p) {
    int e = eids[p];
    acc += vals[e] * Msrc[(size_t)other[e] * 64 + lane];
  }
  T[(size_t)wid * 64 + lane] += acc;
}

// ---------------- two-stage gram: G[a,c] = sum_i A[i,a]*B[i,c], Ka in {16,64} ----------------
__global__ __launch_bounds__(256) void gram_partial(const float* __restrict__ A, const float* __restrict__ B,
                                                    float* __restrict__ P, int n, int Ka, int chunk)
{
  __shared__ float sA[8 * 64];
  __shared__ float sB[8 * 64];
  const int t = threadIdx.x;
  const int tpa = 256 / Ka;
  const int cpt = 64 / tpa;
  const int a  = t / tpa;
  const int c0 = (t % tpa) * cpt;
  float acc[16];
#pragma unroll
  for (int j = 0; j < 16; j++) acc[j] = 0.f;
  int r0 = blockIdx.x * chunk;
  int r1 = min(n, r0 + chunk);
  for (int rb = r0; rb < r1; rb += 8) {
    int nb = min(8, r1 - rb);
    for (int q = t; q < nb * Ka; q += 256) sA[(q / Ka) * 64 + (q % Ka)] = A[(size_t)(rb + q / Ka) * Ka + (q % Ka)];
    for (int q = t; q < nb * 64; q += 256) sB[q] = B[(size_t)rb * 64 + q];
    __syncthreads();
    for (int r = 0; r < nb; r++) {
      float av = sA[r * 64 + a];
      const float* sb = &sB[r * 64 + c0];
      if (cpt == 16) {
#pragma unroll
        for (int j = 0; j < 16; j++) acc[j] += av * sb[j];
      } else {
#pragma unroll
        for (int j = 0; j < 4; j++) acc[j] += av * sb[j];
      }
    }
    __syncthreads();
  }
  float* p = P + (size_t)blockIdx.x * Ka * 64 + a * 64 + c0;
  if (cpt == 16) {
#pragma unroll
    for (int j = 0; j < 16; j++) p[j] = acc[j];
  } else {
#pragma unroll
    for (int j = 0; j < 4; j++) p[j] = acc[j];
  }
}

__global__ void gram_reduce(const float* __restrict__ P, float* __restrict__ G, int cells, int parts)
{
  int c = blockIdx.x * 256 + threadIdx.x;
  if (c >= cells) return;
  float s = 0.f;
  for (int p = 0; p < parts; p++) s += P[(size_t)p * cells + c];
  G[c] = s;
}

// ---------------- SPD inverse (no pivoting), 2 barriers/step ----------------
__global__ __launch_bounds__(256) void inverse64_spd(const float* __restrict__ G, float* __restrict__ Gi,
                                                     float alpha, float beta)
{
  __shared__ __align__(16) float A[64 * 132];
  __shared__ __align__(16) float prow[128];
  __shared__ float fcol[64];
  const int t = threadIdx.x;
  for (int q = t; q < 64 * 128; q += 256) {
    int r = q >> 7, c = q & 127;
    float v;
    if (c < 64) v = alpha * G[r * 64 + c] + ((c == r) ? beta : 0.f);
    else        v = (c - 64 == r) ? 1.f : 0.f;
    A[r * 132 + c] = v;
  }
  __syncthreads();
  const int i  = t >> 2;
  const int c0 = (t & 3) * 32;
  for (int k = 0; k < 64; k++) {
    if (t < 128) prow[t] = A[k * 132 + t];
    else if (t < 192) fcol[t - 128] = A[(t - 128) * 132 + k];
    __syncthreads();
    float pinv = 1.f / prow[k];
    float f = fcol[i];
    float4* Ar = reinterpret_cast<float4*>(&A[i * 132 + c0]);
    const float4* pr = reinterpret_cast<const float4*>(&prow[c0]);
    if (i == k) {
#pragma unroll
      for (int j = 0; j < 8; j++) {
        float4 p = pr[j];
        p.x *= pinv; p.y *= pinv; p.z *= pinv; p.w *= pinv;
        Ar[j] = p;
      }
    } else {
#pragma unroll
      for (int j = 0; j < 8; j++) {
        float4 p = pr[j]; float4 av = Ar[j];
        av.x -= f * (p.x * pinv); av.y -= f * (p.y * pinv);
        av.z -= f * (p.z * pinv); av.w -= f * (p.w * pinv);
        Ar[j] = av;
      }
    }
    __syncthreads();
  }
  for (int q = t; q < 4096; q += 256) Gi[q] = A[(q >> 6) * 132 + 64 + (q & 63)];
}

// score[e] = ew[e] - dot64(Ma[row[e]], Mb[col[e]]); also zeroes hist1 for the next pass
__global__ void edge_score(const float* __restrict__ ew, const int* __restrict__ row,
                           const int* __restrict__ col, const float* __restrict__ Ma,
                           const float* __restrict__ Mb, float* __restrict__ score,
                           int* __restrict__ hist1, int E)
{
  int e = blockIdx.x * 256 + threadIdx.x;
  if (e < 4096) hist1[e] = 0;
  if (e >= E) return;
  const float4* a = reinterpret_cast<const float4*>(Ma + (size_t)row[e] * 64);
  const float4* b = reinterpret_cast<const float4*>(Mb + (size_t)col[e] * 64);
  float s = 0.f;
#pragma unroll
  for (int q = 0; q < 16; q++) {
    float4 av = a[q], bv = b[q];
    s += av.x * bv.x + av.y * bv.y + av.z * bv.z + av.w * bv.w;
  }
  score[e] = ew[e] - s;
}

// ---- exact order-statistic selection on S = score^2 ----
__global__ void hist_pass1(const float* __restrict__ score, int* __restrict__ h,
                           int* __restrict__ h2a, int* __restrict__ h2b, int E)
{
  int e = blockIdx.x * 256 + threadIdx.x;
  if (e < 4096) { h2a[e] = 0; h2b[e] = 0; }
  if (e >= E) return;
  float sc = score[e];
  unsigned u = __float_as_uint(sc * sc);
  atomicAdd(&h[u >> 20], 1);
}

__global__ void hist_pass2(const float* __restrict__ score, const SelState* __restrict__ sel,
                           int* __restrict__ h2a, int* __restrict__ h2b,
                           int* __restrict__ h3a, int* __restrict__ h3b, int E)
{
  int e = blockIdx.x * 256 + threadIdx.x;
  if (e < 256) { h3a[e] = 0; h3b[e] = 0; }
  if (e >= E) return;
  float sc = score[e];
  unsigned u = __float_as_uint(sc * sc);
  int top = (int)(u >> 20);
  if (top == sel->bin1[0]) atomicAdd(&h2a[(u >> 8) & 0xFFF], 1);
  if (top == sel->bin1[1]) atomicAdd(&h2b[(u >> 8) & 0xFFF], 1);
}

__global__ void hist_pass3(const float* __restrict__ score, const SelState* __restrict__ sel,
                           int* __restrict__ h3a, int* __restrict__ h3b, int E)
{
  int e = blockIdx.x * 256 + threadIdx.x;
  if (e >= E) return;
  float sc = score[e];
  unsigned u = __float_as_uint(sc * sc);
  int pre = (int)(u >> 8);
  if (pre == ((sel->bin1[0] << 12) | sel->bin2[0])) atomicAdd(&h3a[u & 255], 1);
  if (pre == ((sel->bin1[1] << 12) | sel->bin2[1])) atomicAdd(&h3b[u & 255], 1);
}

__global__ __launch_bounds__(256) void select_scan(
    const int* __restrict__ h0, const int* __restrict__ h1,
    int nbins, int stage, SelState* sel)
{
  const int t = threadIdx.x;
  __shared__ int part[256];
  __shared__ int foundBin[2];
  __shared__ float qsh[2];
  const int per = nbins / 256;
  for (int tgt = 0; tgt < 2; tgt++) {
    const int* H = tgt ? h1 : h0;
    int R;
    if (stage == 1)      R = tgt ? (3 * kE / 4) : (kE / 4);
    else if (stage == 2) R = sel->rem1[tgt];
    else                 R = sel->rem2[tgt];
    int lsum = 0;
    for (int b = 0; b < per; b++) lsum += H[t * per + b];
    part[t] = lsum;
    __syncthreads();
    for (int off = 1; off < 256; off <<= 1) {
      int v = part[t];
      int u = (t >= off) ? part[t - off] : 0;
      __syncthreads();
      part[t] = v + u;
      __syncthreads();
    }
    int cum = part[t] - lsum;
    int fb = -1, fr = 0;
    for (int b = 0; b < per; b++) {
      int c = H[t * per + b];
      if (R >= cum && R < cum + c) { fb = t * per + b; fr = R - cum; }
      cum += c;
    }
    if (fb >= 0) {
      foundBin[tgt] = fb;
      if (stage == 1) { sel->bin1[tgt] = fb; sel->rem1[tgt] = fr; }
      else if (stage == 2) { sel->bin2[tgt] = fb; sel->rem2[tgt] = fr; }
    }
    __syncthreads();
    if (stage == 3 && t == 0) {
      unsigned u = ((unsigned)sel->bin1[tgt] << 20) | ((unsigned)sel->bin2[tgt] << 8)
                 | (unsigned)foundBin[tgt];
      qsh[tgt] = __uint_as_float(u);
    }
    __syncthreads();
  }
  if (stage == 3 && t == 0) {
    float q1 = qsh[0], q3 = qsh[1];
    sel->thr_base = q3 + 1.5f * (q3 - q1);
  }
}

__global__ void mask_SS(const float* __restrict__ score, const float* __restrict__ conf,
                        const SelState* __restrict__ sel, const float* __restrict__ bp,
                        float* __restrict__ SS, int E)
{
  int e = blockIdx.x * 256 + threadIdx.x;
  if (e >= E) return;
  float sc = score[e];
  float thr = sel->thr_base * conf[e];
  SS[e] = (sc * sc < thr) ? (sc + bp[0]) : 0.f;
}

// T[i,k] = sum_j X[i,j]*G[j,k] + EPS * sum_c hc[i,c]*hTX[c,k]
__global__ void base_temp(const float* __restrict__ X, const float* __restrict__ G,
                          const float* __restrict__ hc, const float* __restrict__ hTX,
                          float* __restrict__ T, int n)
{
  int t = blockIdx.x * 256 + threadIdx.x;
  if (t >= n * 64) return;
  int i = t >> 6, k = t & 63;
  const float* xi = X + (size_t)i * 64;
  float s = 0.f;
#pragma unroll 8
  for (int j = 0; j < 64; j++) s += xi[j] * G[j * 64 + k];
  float s2 = 0.f;
#pragma unroll
  for (int c = 0; c < 16; c++) s2 += hc[(size_t)i * 16 + c] * hTX[c * 64 + k];
  T[t] = s + 0.1f * s2;
}

__global__ void mul_right64(const float* __restrict__ T, const float* __restrict__ Gi,
                            float* __restrict__ Out, int n)
{
  int t = blockIdx.x * 256 + threadIdx.x;
  if (t >= n * 64) return;
  int i = t >> 6, k = t & 63;
  const float* ti = T + (size_t)i * 64;
  float s = 0.f;
#pragma unroll 8
  for (int j = 0; j < 64; j++) s += ti[j] * Gi[j * 64 + k];
  Out[t] = s;
}

__global__ __launch_bounds__(256) void final_out(
    const float* __restrict__ Um, const float* __restrict__ hTV,
    const float* __restrict__ hc, const float* __restrict__ Wm,
    float* __restrict__ out, int n)
{
  __shared__ float sh[1024];
  __shared__ float sW[256];
  for (int q = threadIdx.x; q < 1024; q += 256) sh[q] = hTV[q];
  sW[threadIdx.x] = Wm[threadIdx.x & 255];
  __syncthreads();
  int i = blockIdx.x * 256 + threadIdx.x;
  if (i >= n) return;
  const float* u = Um + (size_t)i * 64;
  float pre[16];
#pragma unroll
  for (int c = 0; c < 16; c++) {
    float s = 0.f;
#pragma unroll
    for (int k = 0; k < 64; k++) s += u[k] * sh[c * 64 + k];
    pre[c] = 0.9f * s + 0.1f * hc[(size_t)i * 16 + c];
  }
#pragma unroll
  for (int j = 0; j < 16; j++) {
    float o = 0.f;
#pragma unroll
    for (int c = 0; c < 16; c++) o += pre[c] * sW[c * 16 + j];
    out[(size_t)i * 16 + j] = o;
  }
}

extern "C" void kernel_launch(void* const* d_in, const int* in_sizes, int n_in,
                              void* d_out, int out_size, void* d_ws, size_t ws_size,
                              hipStream_t stream)
{
  const float* x       = (const float*)d_in[0];
  const int*   eidx    = (const int*)d_in[1];
  const float* ew      = (const float*)d_in[2];
  const float* aw      = (const float*)d_in[3];
  const float* connect = (const float*)d_in[4];
  const float* ci      = (const float*)d_in[5];
  const float* lin1_w  = (const float*)d_in[6];
  const float* lin1_b  = (const float*)d_in[7];
  const float* lin2_w  = (const float*)d_in[8];
  const float* lin2_b  = (const float*)d_in[9];
  const float* lin_a_w = (const float*)d_in[10];
  const float* lin_a_b = (const float*)d_in[11];
  const float* lin_n_w = (const float*)d_in[12];
  const float* lin_n_b = (const float*)d_in[13];
  const float* left_w  = (const float*)d_in[14];
  const float* att_w   = (const float*)d_in[15];
  const float* v_w     = (const float*)d_in[16];
  const float* v_b     = (const float*)d_in[17];
  const float* Wm      = (const float*)d_in[18];
  const float* conf_p  = (const float*)d_in[19];
  const float* b_param = (const float*)d_in[20];
  const int* row = eidx;
  const int* col = eidx + kE;
  float* out = (float*)d_out;

  char* base = (char*)d_ws;
  size_t off = 0;
  auto alloc = [&](size_t bytes) -> void* {
    void* p = base + off;
    off += bytes;
    off = (off + 255) & ~(size_t)255;
    return p;
  };
  float* xa    = (float*)alloc((size_t)kN * kNH * 4);
  float* raw   = (float*)alloc((size_t)kN * kNH * 4);
  float* h16   = (float*)alloc((size_t)kN * kC * 4);
  float* hC    = (float*)alloc((size_t)kN * kC * 4);
  float* nei   = (float*)alloc((size_t)kN * kC * 4);
  float* lx    = (float*)alloc((size_t)kN * kC * 4);
  int*   yhat  = (int*)alloc((size_t)kN * 4);
  float* conf  = (float*)alloc((size_t)kE * 4);
  float* V     = (float*)alloc((size_t)kN * kK * 4);
  float* U     = (float*)alloc((size_t)kN * kK * 4);
  float* T     = (float*)alloc((size_t)kN * kK * 4);
  float* score = (float*)alloc((size_t)kE * 4);
  float* SS    = (float*)alloc((size_t)kE * 4);
  float* G     = (float*)alloc(64 * 64 * 4);
  float* Gi    = (float*)alloc(64 * 64 * 4);
  float* hTX   = (float*)alloc(kC * kK * 4);
  int* hist1   = (int*)alloc(4096 * 4);
  int* h2a     = (int*)alloc(4096 * 4);
  int* h2b     = (int*)alloc(4096 * 4);
  int* h3a     = (int*)alloc(256 * 4);
  int* h3b     = (int*)alloc(256 * 4);
  SelState* sel = (SelState*)alloc(sizeof(SelState));
  float* wsoft = (float*)alloc(4 * 4);
  int* cntR    = (int*)alloc((size_t)kN * 4);
  int* cntC    = (int*)alloc((size_t)kN * 4);
  int* fillR   = (int*)alloc((size_t)kN * 4);
  int* fillC   = (int*)alloc((size_t)kN * 4);
  int* startR  = (int*)alloc((size_t)(kN + 1) * 4);
  int* startC  = (int*)alloc((size_t)(kN + 1) * 4);
  int* eR      = (int*)alloc((size_t)kE * 4);
  int* eC      = (int*)alloc((size_t)kE * 4);
  float* P     = (float*)alloc((size_t)100 * 4096 * 4);

  const int eg  = (kE + 255) / 256;
  const int nkg = (kN * kK + 255) / 256;
  const int gwg = (kN + 3) / 4;  // spmm_gather: 4 waves/block, wave per row

  // ---- CSR build (once per call) ----
  // FIX(R3): span via pointer-diff — alloc() pads each array to 256B, so
  // 4*kN*4 left fillC's tail poisoned (R2 core dump: garbage atomic offsets).
  {
    size_t csrSpan = (size_t)((char*)(fillC + kN) - (char*)cntR);
    (void)hipMemsetAsync(cntR, 0, csrSpan, stream);
  }
  csr_count<<<eg, 256, 0, stream>>>(row, col, cntR, cntC, kE);
  scan2<<<1, 1024, 0, stream>>>(cntR, cntC, startR, startC, kN);
  csr_fill<<<eg, 256, 0, stream>>>(row, col, startR, startC, fillR, fillC, eR, eC, kE);

  // ---- dense front-end ----
  gemm_sbf16<<<dim3(125, 2), 256, 0, stream>>>(connect, lin_a_w, lin_a_b, xa, kN);
  gemm_sbf16<<<dim3(125, 2), 256, 0, stream>>>(x, lin1_w, lin1_b, raw, 500);
  combine_relu4<<<(kN * kNH / 4 + 255) / 256, 256, 0, stream>>>(
      (const float4*)raw, (const float4*)xa, (float4*)raw, kN * kNH / 4);
  gemm_rowdot<<<(kN * kC + 255) / 256, 256, 0, stream>>>(raw, lin2_w, lin2_b, h16, kN, kC, kNH);
  argmax16<<<(kN + 255) / 256, 256, 0, stream>>>(h16, yhat, kN);
  (void)hipMemsetAsync(nei, 0, (size_t)kN * kC * 4, stream);
  scatter_nei<<<eg, 256, 0, stream>>>(row, col, aw, yhat, nei, kE);
  norm_xn_h<<<(kN + 255) / 256, 256, 0, stream>>>(nei, h16, lin_n_w, lin_n_b, hC, kN);
  gemm_rowdot<<<(kN * kC + 255) / 256, 256, 0, stream>>>(hC, left_w, nullptr, lx, kN, kC, kC);
  softmax3<<<1, 1, 0, stream>>>(conf_p, wsoft);
  edge_conf<<<eg, 256, 0, stream>>>(row, col, lx, att_w, ci, wsoft, conf, kE);
  gemm_rowdot<<<(kN * kK + 255) / 256, 256, 0, stream>>>(raw, v_w, v_b, V, kN, kK, kNH);

  // ---- U init: U = spmm(aw,row,V[col]) @ inv(V^T V) ----
  gram_partial<<<100, 256, 0, stream>>>(V, V, P, kN, 64, 100);
  gram_reduce<<<16, 256, 0, stream>>>(P, G, 4096, 100);
  inverse64_spd<<<1, 256, 0, stream>>>(G, Gi, 1.0f, 0.0f);
  (void)hipMemsetAsync(T, 0, (size_t)kN * kK * 4, stream);
  spmm_gather<<<gwg, 256, 0, stream>>>(aw, startR, eR, col, V, T, kN);
  mul_right64<<<nkg, 256, 0, stream>>>(T, Gi, U, kN);

  for (int j = 0; j < 4; j++) {
    bool upd_u = ((j & 1) == 0);
    const float* Ma = upd_u ? U : V;
    const float* Mb = upd_u ? V : U;
    edge_score<<<eg, 256, 0, stream>>>(ew, row, col, Ma, Mb, score, hist1, kE);
    hist_pass1<<<eg, 256, 0, stream>>>(score, hist1, h2a, h2b, kE);
    select_scan<<<1, 256, 0, stream>>>(hist1, hist1, 4096, 1, sel);
    hist_pass2<<<eg, 256, 0, stream>>>(score, sel, h2a, h2b, h3a, h3b, kE);
    select_scan<<<1, 256, 0, stream>>>(h2a, h2b, 4096, 2, sel);
    hist_pass3<<<eg, 256, 0, stream>>>(score, sel, h3a, h3b, kE);
    select_scan<<<1, 256, 0, stream>>>(h3a, h3b, 256, 3, sel);
    mask_SS<<<eg, 256, 0, stream>>>(score, conf, sel, b_param, SS, kE);

    const float* Xcur = upd_u ? U : V;
    const float* Moth = upd_u ? V : U;
    gram_partial<<<100, 256, 0, stream>>>(Moth, Moth, P, kN, 64, 100);
    gram_reduce<<<16, 256, 0, stream>>>(P, G, 4096, 100);
    gram_partial<<<100, 256, 0, stream>>>(hC, Moth, P, kN, 16, 100);
    gram_reduce<<<4, 256, 0, stream>>>(P, hTX, 1024, 100);
    inverse64_spd<<<1, 256, 0, stream>>>(G, Gi, 1.1f, 1.0f);
    base_temp<<<nkg, 256, 0, stream>>>(Xcur, G, hC, hTX, T, kN);
    if (upd_u) spmm_gather<<<gwg, 256, 0, stream>>>(SS, startR, eR, col, V, T, kN);
    else       spmm_gather<<<gwg, 256, 0, stream>>>(SS, startC, eC, row, U, T, kN);
    mul_right64<<<nkg, 256, 0, stream>>>(T, Gi, upd_u ? U : V, kN);
  }

  gram_partial<<<100, 256, 0, stream>>>(hC, V, P, kN, 16, 100);
  gram_reduce<<<4, 256, 0, stream>>>(P, hTX, 1024, 100);
  final_out<<<(kN + 255) / 256, 256, 0, stream>>>(U, hTX, hC, Wm, out, kN);
}

// Round 5
// 4346.730 us; speedup vs baseline: 1.5816x; 1.1602x over previous
//
#include <hip/hip_runtime.h>
#include <cstddef>
#include <cstdint>

// Round 5: big-GEMM rebuilt for occupancy (R4 was 1 block/CU, MfmaUtil 5%):
//   BM=64 BN=128 BK=32, split-K x4 -> 1256 blocks (~4-5/CU), partial buffers
//   + fused reduce(bias+bias+relu-combine). V via MFMA (BN=64 variant);
//   gemm_rowdot kept only for h16/lx.

constexpr int kN  = 10000;
constexpr int kE  = 320000;
constexpr int kNH = 256;
constexpr int kC  = 16;
constexpr int kK  = 64;

struct SelState {
  int bin1[2]; int rem1[2];
  int bin2[2]; int rem2[2];
  float thr_base;
};

typedef short bf16x8 __attribute__((ext_vector_type(8)));
typedef float f32x4 __attribute__((ext_vector_type(4)));

__device__ __forceinline__ ushort f2bf(float x) {
  unsigned u = __float_as_uint(x);
  unsigned r = (u + 0x7fffu + ((u >> 16) & 1u)) >> 16;   // RNE
  return (ushort)r;
}
__device__ __forceinline__ float bf2f(ushort h) {
  return __uint_as_float((unsigned)h << 16);
}

// ===== split-bf16 MFMA GEMM, split-K partials =====
// out[ks] += A[bm:bm+64, k0:kend] @ B[bn:bn+BN, ...]^T  (3-term hi/lo split)
// grid (ceil(M/64), N2/BN, nsplit); KR = K/nsplit (multiple of 4).
template<int BN>
__global__ __launch_bounds__(256) void gemm_skbf16(
    const float* __restrict__ A, const float* __restrict__ B,
    const float* __restrict__ bias, float* __restrict__ out,
    int M, int K, int KR, int outStride)
{
  constexpr int NBF = BN / 32;      // col frags per wave (4 or 2)
  constexpr int LDT = 40;           // ushort stride/row: 32 data + 8 pad (16B-aligned reads)
  __shared__ __align__(16) ushort Ah[64 * LDT];
  __shared__ __align__(16) ushort Al[64 * LDT];
  __shared__ __align__(16) ushort Bh[BN * LDT];
  __shared__ __align__(16) ushort Bl[BN * LDT];
  const int t = threadIdx.x;
  const int bm = blockIdx.x * 64;
  const int bn = blockIdx.y * BN;
  const int k0 = blockIdx.z * KR;
  const int kend = min(K, k0 + KR);
  out += (size_t)blockIdx.z * M * outStride;
  const int lane = t & 63, w = t >> 6;
  const int wr = (w >> 1) * 32;           // wave row offset in tile
  const int wc = (w & 1) * (BN / 2);      // wave col offset in tile
  const int l15 = lane & 15, lhi8 = (lane >> 4) * 8;

  f32x4 acc[2][NBF] = {};
  for (int kt = k0; kt < kend; kt += 32) {
    // stage A 64x32 (2 float4/thread), convert to hi/lo bf16
#pragma unroll
    for (int i2 = 0; i2 < 2; i2++) {
      int idx = t + i2 * 256;
      int r = idx >> 3, kc = (idx & 7) << 2;
      int gr = bm + r, gk = kt + kc;
      float4 v = make_float4(0.f, 0.f, 0.f, 0.f);
      if (gr < M && gk + 4 <= kend)
        v = *reinterpret_cast<const float4*>(A + (size_t)gr * K + gk);
      ushort4 hi, lo;
      hi.x = f2bf(v.x); lo.x = f2bf(v.x - bf2f(hi.x));
      hi.y = f2bf(v.y); lo.y = f2bf(v.y - bf2f(hi.y));
      hi.z = f2bf(v.z); lo.z = f2bf(v.z - bf2f(hi.z));
      hi.w = f2bf(v.w); lo.w = f2bf(v.w - bf2f(hi.w));
      *reinterpret_cast<ushort4*>(&Ah[r * LDT + kc]) = hi;
      *reinterpret_cast<ushort4*>(&Al[r * LDT + kc]) = lo;
    }
    // stage B BNx32 (NBF float4/thread)
#pragma unroll
    for (int i2 = 0; i2 < NBF; i2++) {
      int idx = t + i2 * 256;
      int r = idx >> 3, kc = (idx & 7) << 2;
      int gk = kt + kc;
      float4 v = make_float4(0.f, 0.f, 0.f, 0.f);
      if (gk + 4 <= kend)
        v = *reinterpret_cast<const float4*>(B + (size_t)(bn + r) * K + gk);
      ushort4 hi, lo;
      hi.x = f2bf(v.x); lo.x = f2bf(v.x - bf2f(hi.x));
      hi.y = f2bf(v.y); lo.y = f2bf(v.y - bf2f(hi.y));
      hi.z = f2bf(v.z); lo.z = f2bf(v.z - bf2f(hi.z));
      hi.w = f2bf(v.w); lo.w = f2bf(v.w - bf2f(hi.w));
      *reinterpret_cast<ushort4*>(&Bh[r * LDT + kc]) = hi;
      *reinterpret_cast<ushort4*>(&Bl[r * LDT + kc]) = lo;
    }
    __syncthreads();
    bf16x8 bhh[NBF], bll[NBF];
#pragma unroll
    for (int nb = 0; nb < NBF; nb++) {
      int rr = wc + nb * 16 + l15;
      bhh[nb] = *reinterpret_cast<const bf16x8*>(&Bh[rr * LDT + lhi8]);
      bll[nb] = *reinterpret_cast<const bf16x8*>(&Bl[rr * LDT + lhi8]);
    }
#pragma unroll
    for (int rb = 0; rb < 2; rb++) {
      int rr = wr + rb * 16 + l15;
      bf16x8 ahh = *reinterpret_cast<const bf16x8*>(&Ah[rr * LDT + lhi8]);
      bf16x8 all = *reinterpret_cast<const bf16x8*>(&Al[rr * LDT + lhi8]);
#pragma unroll
      for (int nb = 0; nb < NBF; nb++) {
        acc[rb][nb] = __builtin_amdgcn_mfma_f32_16x16x32_bf16(ahh, bhh[nb], acc[rb][nb], 0, 0, 0);
        acc[rb][nb] = __builtin_amdgcn_mfma_f32_16x16x32_bf16(all, bhh[nb], acc[rb][nb], 0, 0, 0);
        acc[rb][nb] = __builtin_amdgcn_mfma_f32_16x16x32_bf16(ahh, bll[nb], acc[rb][nb], 0, 0, 0);
      }
    }
    __syncthreads();
  }
  // epilogue (validated layout: col = l15-based, row = (lane>>4)*4+j)
#pragma unroll
  for (int rb = 0; rb < 2; rb++) {
#pragma unroll
    for (int nb = 0; nb < NBF; nb++) {
      int colg = bn + wc + nb * 16 + l15;
      float bv = bias ? bias[colg] : 0.f;
#pragma unroll
      for (int j = 0; j < 4; j++) {
        int rowg = bm + wr + rb * 16 + (lane >> 4) * 4 + j;
        if (rowg < M) out[(size_t)rowg * outStride + colg] = acc[rb][nb][j] + bv;
      }
    }
  }
}

// raw = relu(0.5*(sum4(Pa) + ba) + 0.5*(Px + b1)); float4 over [kN,256]
__global__ void reduce_raw(const float4* __restrict__ Pa, const float4* __restrict__ Px,
                           const float* __restrict__ ba, const float* __restrict__ b1,
                           float4* __restrict__ raw)
{
  int t = blockIdx.x * 256 + threadIdx.x;
  if (t >= kN * kNH / 4) return;
  const int sl = kN * kNH / 4;
  float4 s0 = Pa[t], s1 = Pa[t + sl], s2 = Pa[t + 2 * sl], s3 = Pa[t + 3 * sl];
  float4 px = Px[t];
  int c4 = t & 63;
  float4 vba = reinterpret_cast<const float4*>(ba)[c4];
  float4 vb1 = reinterpret_cast<const float4*>(b1)[c4];
  float4 r;
  r.x = fmaxf(0.5f * (s0.x + s1.x + s2.x + s3.x + vba.x) + 0.5f * (px.x + vb1.x), 0.f);
  r.y = fmaxf(0.5f * (s0.y + s1.y + s2.y + s3.y + vba.y) + 0.5f * (px.y + vb1.y), 0.f);
  r.z = fmaxf(0.5f * (s0.z + s1.z + s2.z + s3.z + vba.z) + 0.5f * (px.z + vb1.z), 0.f);
  r.w = fmaxf(0.5f * (s0.w + s1.w + s2.w + s3.w + vba.w) + 0.5f * (px.w + vb1.w), 0.f);
  raw[t] = r;
}

__global__ void gemm_rowdot(const float* __restrict__ A, const float* __restrict__ Bw,
                            const float* __restrict__ bias, float* __restrict__ outm,
                            int M, int N2, int K2)
{
  int t = blockIdx.x * 256 + threadIdx.x;
  if (t >= M * N2) return;
  int i = t / N2, j = t % N2;
  const float4* a = reinterpret_cast<const float4*>(A + (size_t)i * K2);
  const float4* b = reinterpret_cast<const float4*>(Bw + (size_t)j * K2);
  float s = bias ? bias[j] : 0.f;
  int q4 = K2 >> 2;
  for (int q = 0; q < q4; q++) {
    float4 av = a[q], bv = b[q];
    s += av.x * bv.x + av.y * bv.y + av.z * bv.z + av.w * bv.w;
  }
  outm[t] = s;
}

__global__ void argmax16(const float* __restrict__ h, int* __restrict__ y, int n)
{
  int i = blockIdx.x * 256 + threadIdx.x;
  if (i >= n) return;
  const float* r = h + (size_t)i * 16;
  float m = r[0]; int a = 0;
#pragma unroll
  for (int j = 1; j < 16; j++) { float v = r[j]; if (v > m) { m = v; a = j; } }
  y[i] = a;
}

__global__ void scatter_nei(const int* __restrict__ row, const int* __restrict__ col,
                            const float* __restrict__ aw, const int* __restrict__ yhat,
                            float* nei, int E)
{
  int e = blockIdx.x * 256 + threadIdx.x;
  if (e >= E) return;
  atomicAdd(&nei[(size_t)row[e] * 16 + yhat[col[e]]], aw[e]);
}

__global__ void norm_xn_h(const float* __restrict__ nei, const float* __restrict__ h16,
                          const float* __restrict__ lnw, const float* __restrict__ lnb,
                          float* __restrict__ hc, int n)
{
  int i = blockIdx.x * 256 + threadIdx.x;
  if (i >= n) return;
  float nv[16]; float s = 0.f;
#pragma unroll
  for (int c = 0; c < 16; c++) { nv[c] = nei[(size_t)i * 16 + c]; s += nv[c]; }
  float inv = (s != 0.f) ? 1.f / s : 0.f;
#pragma unroll
  for (int j = 0; j < 16; j++) {
    float xn = lnb[j];
#pragma unroll
    for (int c = 0; c < 16; c++) xn += (nv[c] * inv) * lnw[j * 16 + c];
    xn = fmaxf(xn, 0.f);
    hc[(size_t)i * 16 + j] = 0.5f * h16[(size_t)i * 16 + j] + 0.5f * xn;
  }
}

__global__ void softmax3(const float* __restrict__ p, float* __restrict__ w)
{
  float a = p[0], b = p[1], c = p[2];
  float m = fmaxf(a, fmaxf(b, c));
  float ea = expf(a - m), eb = expf(b - m), ec = expf(c - m);
  float s = ea + eb + ec;
  w[0] = ea / s; w[1] = eb / s; w[2] = ec / s;
}

__global__ void edge_conf(const int* __restrict__ row, const int* __restrict__ col,
                          const float* __restrict__ lx, const float* __restrict__ attw,
                          const float* __restrict__ ci, const float* __restrict__ wsoft,
                          float* __restrict__ conf, int E)
{
  int e = blockIdx.x * 256 + threadIdx.x;
  if (e >= E) return;
  const float* a = lx + (size_t)row[e] * 16;
  const float* b = lx + (size_t)col[e] * 16;
  float s = 0.f;
#pragma unroll
  for (int c = 0; c < 16; c++) s += fmaxf(a[c] + b[c], 0.f) * attw[c];
  float cf = 1.f / (1.f + expf(-s));
  conf[e] = cf * wsoft[0] + ci[e] * wsoft[1] + ci[(size_t)E + e] * wsoft[2];
}

// ---------------- CSR build ----------------
__global__ void csr_count(const int* __restrict__ row, const int* __restrict__ col,
                          int* cntR, int* cntC, int E)
{
  int e = blockIdx.x * 256 + threadIdx.x;
  if (e >= E) return;
  atomicAdd(&cntR[row[e]], 1);
  atomicAdd(&cntC[col[e]], 1);
}

__global__ __launch_bounds__(1024) void scan2(const int* __restrict__ cntR, const int* __restrict__ cntC,
                                              int* __restrict__ startR, int* __restrict__ startC, int n)
{
  __shared__ int part[1024];
  const int t = threadIdx.x;
  for (int pass = 0; pass < 2; ++pass) {
    const int* cnt = pass ? cntC : cntR;
    int* start = pass ? startC : startR;
    int base = t * 10;
    int loc[10]; int s = 0;
#pragma unroll
    for (int q = 0; q < 10; q++) { int idx = base + q; int v = (idx < n) ? cnt[idx] : 0; loc[q] = v; s += v; }
    part[t] = s;
    __syncthreads();
    for (int off = 1; off < 1024; off <<= 1) {
      int v = part[t];
      int u = (t >= off) ? part[t - off] : 0;
      __syncthreads();
      part[t] = v + u;
      __syncthreads();
    }
    int run = part[t] - s;
#pragma unroll
    for (int q = 0; q < 10; q++) { int idx = base + q; if (idx < n) start[idx] = run; run += loc[q]; }
    if (t == 1023) start[n] = part[1023];
    __syncthreads();
  }
}

__global__ void csr_fill(const int* __restrict__ row, const int* __restrict__ col,
                         const int* __restrict__ startR, const int* __restrict__ startC,
                         int* fillR, int* fillC, int* eR, int* eC, int E)
{
  int e = blockIdx.x * 256 + threadIdx.x;
  if (e >= E) return;
  int r = row[e]; eR[startR[r] + atomicAdd(&fillR[r], 1)] = e;
  int c = col[e]; eC[startC[c] + atomicAdd(&fillC[c], 1)] = e;
}

// T[i,:] += sum over edges of segment i: vals[e] * Msrc[other[e],:]   (wave per row)
__global__ void spmm_gather(const float* __restrict__ vals, const int* __restrict__ start,
                            const int* __restrict__ eids, const int* __restrict__ other,
                            const float* __restrict__ Msrc, float* __restrict__ T, int n)
{
  int wid = blockIdx.x * 4 + (threadIdx.x >> 6);
  int lane = threadIdx.x & 63;
  if (wid >= n) return;
  int p = start[wid], pend = start[wid + 1];
  float acc = 0.f;
  for (; p < pend; ++p) {
    int e = eids[p];
    acc += vals[e] * Msrc[(size_t)other[e] * 64 + lane];
  }
  T[(size_t)wid * 64 + lane] += acc;
}

// ---------------- two-stage gram ----------------
__global__ __launch_bounds__(256) void gram_partial(const float* __restrict__ A, const float* __restrict__ B,
                                                    float* __restrict__ P, int n, int Ka, int chunk)
{
  __shared__ float sA[8 * 64];
  __shared__ float sB[8 * 64];
  const int t = threadIdx.x;
  const int tpa = 256 / Ka;
  const int cpt = 64 / tpa;
  const int a  = t / tpa;
  const int c0 = (t % tpa) * cpt;
  float acc[16];
#pragma unroll
  for (int j = 0; j < 16; j++) acc[j] = 0.f;
  int r0 = blockIdx.x * chunk;
  int r1 = min(n, r0 + chunk);
  for (int rb = r0; rb < r1; rb += 8) {
    int nb = min(8, r1 - rb);
    for (int q = t; q < nb * Ka; q += 256) sA[(q / Ka) * 64 + (q % Ka)] = A[(size_t)(rb + q / Ka) * Ka + (q % Ka)];
    for (int q = t; q < nb * 64; q += 256) sB[q] = B[(size_t)rb * 64 + q];
    __syncthreads();
    for (int r = 0; r < nb; r++) {
      float av = sA[r * 64 + a];
      const float* sb = &sB[r * 64 + c0];
      if (cpt == 16) {
#pragma unroll
        for (int j = 0; j < 16; j++) acc[j] += av * sb[j];
      } else {
#pragma unroll
        for (int j = 0; j < 4; j++) acc[j] += av * sb[j];
      }
    }
    __syncthreads();
  }
  float* p = P + (size_t)blockIdx.x * Ka * 64 + a * 64 + c0;
  if (cpt == 16) {
#pragma unroll
    for (int j = 0; j < 16; j++) p[j] = acc[j];
  } else {
#pragma unroll
    for (int j = 0; j < 4; j++) p[j] = acc[j];
  }
}

__global__ void gram_reduce(const float* __restrict__ P, float* __restrict__ G, int cells, int parts)
{
  int c = blockIdx.x * 256 + threadIdx.x;
  if (c >= cells) return;
  float s = 0.f;
  for (int p = 0; p < parts; p++) s += P[(size_t)p * cells + c];
  G[c] = s;
}

// ---------------- SPD inverse (no pivoting) ----------------
__global__ __launch_bounds__(256) void inverse64_spd(const float* __restrict__ G, float* __restrict__ Gi,
                                                     float alpha, float beta)
{
  __shared__ __align__(16) float A[64 * 132];
  __shared__ __align__(16) float prow[128];
  __shared__ float fcol[64];
  const int t = threadIdx.x;
  for (int q = t; q < 64 * 128; q += 256) {
    int r = q >> 7, c = q & 127;
    float v;
    if (c < 64) v = alpha * G[r * 64 + c] + ((c == r) ? beta : 0.f);
    else        v = (c - 64 == r) ? 1.f : 0.f;
    A[r * 132 + c] = v;
  }
  __syncthreads();
  const int i  = t >> 2;
  const int c0 = (t & 3) * 32;
  for (int k = 0; k < 64; k++) {
    if (t < 128) prow[t] = A[k * 132 + t];
    else if (t < 192) fcol[t - 128] = A[(t - 128) * 132 + k];
    __syncthreads();
    float pinv = 1.f / prow[k];
    float f = fcol[i];
    float4* Ar = reinterpret_cast<float4*>(&A[i * 132 + c0]);
    const float4* pr = reinterpret_cast<const float4*>(&prow[c0]);
    if (i == k) {
#pragma unroll
      for (int j = 0; j < 8; j++) {
        float4 p = pr[j];
        p.x *= pinv; p.y *= pinv; p.z *= pinv; p.w *= pinv;
        Ar[j] = p;
      }
    } else {
#pragma unroll
      for (int j = 0; j < 8; j++) {
        float4 p = pr[j]; float4 av = Ar[j];
        av.x -= f * (p.x * pinv); av.y -= f * (p.y * pinv);
        av.z -= f * (p.z * pinv); av.w -= f * (p.w * pinv);
        Ar[j] = av;
      }
    }
    __syncthreads();
  }
  for (int q = t; q < 4096; q += 256) Gi[q] = A[(q >> 6) * 132 + 64 + (q & 63)];
}

// score + zero hist1
__global__ void edge_score(const float* __restrict__ ew, const int* __restrict__ row,
                           const int* __restrict__ col, const float* __restrict__ Ma,
                           const float* __restrict__ Mb, float* __restrict__ score,
                           int* __restrict__ hist1, int E)
{
  int e = blockIdx.x * 256 + threadIdx.x;
  if (e < 4096) hist1[e] = 0;
  if (e >= E) return;
  const float4* a = reinterpret_cast<const float4*>(Ma + (size_t)row[e] * 64);
  const float4* b = reinterpret_cast<const float4*>(Mb + (size_t)col[e] * 64);
  float s = 0.f;
#pragma unroll
  for (int q = 0; q < 16; q++) {
    float4 av = a[q], bv = b[q];
    s += av.x * bv.x + av.y * bv.y + av.z * bv.z + av.w * bv.w;
  }
  score[e] = ew[e] - s;
}

// ---- exact order-statistic selection on S = score^2 ----
__global__ void hist_pass1(const float* __restrict__ score, int* __restrict__ h,
                           int* __restrict__ h2a, int* __restrict__ h2b, int E)
{
  int e = blockIdx.x * 256 + threadIdx.x;
  if (e < 4096) { h2a[e] = 0; h2b[e] = 0; }
  if (e >= E) return;
  float sc = score[e];
  unsigned u = __float_as_uint(sc * sc);
  atomicAdd(&h[u >> 20], 1);
}

__global__ void hist_pass2(const float* __restrict__ score, const SelState* __restrict__ sel,
                           int* __restrict__ h2a, int* __restrict__ h2b,
                           int* __restrict__ h3a, int* __restrict__ h3b, int E)
{
  int e = blockIdx.x * 256 + threadIdx.x;
  if (e < 256) { h3a[e] = 0; h3b[e] = 0; }
  if (e >= E) return;
  float sc = score[e];
  unsigned u = __float_as_uint(sc * sc);
  int top = (int)(u >> 20);
  if (top == sel->bin1[0]) atomicAdd(&h2a[(u >> 8) & 0xFFF], 1);
  if (top == sel->bin1[1]) atomicAdd(&h2b[(u >> 8) & 0xFFF], 1);
}

__global__ void hist_pass3(const float* __restrict__ score, const SelState* __restrict__ sel,
                           int* __restrict__ h3a, int* __restrict__ h3b, int E)
{
  int e = blockIdx.x * 256 + threadIdx.x;
  if (e >= E) return;
  float sc = score[e];
  unsigned u = __float_as_uint(sc * sc);
  int pre = (int)(u >> 8);
  if (pre == ((sel->bin1[0] << 12) | sel->bin2[0])) atomicAdd(&h3a[u & 255], 1);
  if (pre == ((sel->bin1[1] << 12) | sel->bin2[1])) atomicAdd(&h3b[u & 255], 1);
}

__global__ __launch_bounds__(256) void select_scan(
    const int* __restrict__ h0, const int* __restrict__ h1,
    int nbins, int stage, SelState* sel)
{
  const int t = threadIdx.x;
  __shared__ int part[256];
  __shared__ int foundBin[2];
  __shared__ float qsh[2];
  const int per = nbins / 256;
  for (int tgt = 0; tgt < 2; tgt++) {
    const int* H = tgt ? h1 : h0;
    int R;
    if (stage == 1)      R = tgt ? (3 * kE / 4) : (kE / 4);
    else if (stage == 2) R = sel->rem1[tgt];
    else                 R = sel->rem2[tgt];
    int lsum = 0;
    for (int b = 0; b < per; b++) lsum += H[t * per + b];
    part[t] = lsum;
    __syncthreads();
    for (int off = 1; off < 256; off <<= 1) {
      int v = part[t];
      int u = (t >= off) ? part[t - off] : 0;
      __syncthreads();
      part[t] = v + u;
      __syncthreads();
    }
    int cum = part[t] - lsum;
    int fb = -1, fr = 0;
    for (int b = 0; b < per; b++) {
      int c = H[t * per + b];
      if (R >= cum && R < cum + c) { fb = t * per + b; fr = R - cum; }
      cum += c;
    }
    if (fb >= 0) {
      foundBin[tgt] = fb;
      if (stage == 1) { sel->bin1[tgt] = fb; sel->rem1[tgt] = fr; }
      else if (stage == 2) { sel->bin2[tgt] = fb; sel->rem2[tgt] = fr; }
    }
    __syncthreads();
    if (stage == 3 && t == 0) {
      unsigned u = ((unsigned)sel->bin1[tgt] << 20) | ((unsigned)sel->bin2[tgt] << 8)
                 | (unsigned)foundBin[tgt];
      qsh[tgt] = __uint_as_float(u);
    }
    __syncthreads();
  }
  if (stage == 3 && t == 0) {
    float q1 = qsh[0], q3 = qsh[1];
    sel->thr_base = q3 + 1.5f * (q3 - q1);
  }
}

__global__ void mask_SS(const float* __restrict__ score, const float* __restrict__ conf,
                        const SelState* __restrict__ sel, const float* __restrict__ bp,
                        float* __restrict__ SS, int E)
{
  int e = blockIdx.x * 256 + threadIdx.x;
  if (e >= E) return;
  float sc = score[e];
  float thr = sel->thr_base * conf[e];
  SS[e] = (sc * sc < thr) ? (sc + bp[0]) : 0.f;
}

// T[i,k] = sum_j X[i,j]*G[j,k] + EPS * sum_c hc[i,c]*hTX[c,k]
__global__ void base_temp(const float* __restrict__ X, const float* __restrict__ G,
                          const float* __restrict__ hc, const float* __restrict__ hTX,
                          float* __restrict__ T, int n)
{
  int t = blockIdx.x * 256 + threadIdx.x;
  if (t >= n * 64) return;
  int i = t >> 6, k = t & 63;
  const float* xi = X + (size_t)i * 64;
  float s = 0.f;
#pragma unroll 8
  for (int j = 0; j < 64; j++) s += xi[j] * G[j * 64 + k];
  float s2 = 0.f;
#pragma unroll
  for (int c = 0; c < 16; c++) s2 += hc[(size_t)i * 16 + c] * hTX[c * 64 + k];
  T[t] = s + 0.1f * s2;
}

__global__ void mul_right64(const float* __restrict__ T, const float* __restrict__ Gi,
                            float* __restrict__ Out, int n)
{
  int t = blockIdx.x * 256 + threadIdx.x;
  if (t >= n * 64) return;
  int i = t >> 6, k = t & 63;
  const float* ti = T + (size_t)i * 64;
  float s = 0.f;
#pragma unroll 8
  for (int j = 0; j < 64; j++) s += ti[j] * Gi[j * 64 + k];
  Out[t] = s;
}

__global__ __launch_bounds__(256) void final_out(
    const float* __restrict__ Um, const float* __restrict__ hTV,
    const float* __restrict__ hc, const float* __restrict__ Wm,
    float* __restrict__ out, int n)
{
  __shared__ float sh[1024];
  __shared__ float sW[256];
  for (int q = threadIdx.x; q < 1024; q += 256) sh[q] = hTV[q];
  sW[threadIdx.x] = Wm[threadIdx.x & 255];
  __syncthreads();
  int i = blockIdx.x * 256 + threadIdx.x;
  if (i >= n) return;
  const float* u = Um + (size_t)i * 64;
  float pre[16];
#pragma unroll
  for (int c = 0; c < 16; c++) {
    float s = 0.f;
#pragma unroll
    for (int k = 0; k < 64; k++) s += u[k] * sh[c * 64 + k];
    pre[c] = 0.9f * s + 0.1f * hc[(size_t)i * 16 + c];
  }
#pragma unroll
  for (int j = 0; j < 16; j++) {
    float o = 0.f;
#pragma unroll
    for (int c = 0; c < 16; c++) o += pre[c] * sW[c * 16 + j];
    out[(size_t)i * 16 + j] = o;
  }
}

extern "C" void kernel_launch(void* const* d_in, const int* in_sizes, int n_in,
                              void* d_out, int out_size, void* d_ws, size_t ws_size,
                              hipStream_t stream)
{
  const float* x       = (const float*)d_in[0];
  const int*   eidx    = (const int*)d_in[1];
  const float* ew      = (const float*)d_in[2];
  const float* aw      = (const float*)d_in[3];
  const float* connect = (const float*)d_in[4];
  const float* ci      = (const float*)d_in[5];
  const float* lin1_w  = (const float*)d_in[6];
  const float* lin1_b  = (const float*)d_in[7];
  const float* lin2_w  = (const float*)d_in[8];
  const float* lin2_b  = (const float*)d_in[9];
  const float* lin_a_w = (const float*)d_in[10];
  const float* lin_a_b = (const float*)d_in[11];
  const float* lin_n_w = (const float*)d_in[12];
  const float* lin_n_b = (const float*)d_in[13];
  const float* left_w  = (const float*)d_in[14];
  const float* att_w   = (const float*)d_in[15];
  const float* v_w     = (const float*)d_in[16];
  const float* v_b     = (const float*)d_in[17];
  const float* Wm      = (const float*)d_in[18];
  const float* conf_p  = (const float*)d_in[19];
  const float* b_param = (const float*)d_in[20];
  const int* row = eidx;
  const int* col = eidx + kE;
  float* out = (float*)d_out;

  char* base = (char*)d_ws;
  size_t off = 0;
  auto alloc = [&](size_t bytes) -> void* {
    void* p = base + off;
    off += bytes;
    off = (off + 255) & ~(size_t)255;
    return p;
  };
  float* raw   = (float*)alloc((size_t)kN * kNH * 4);
  float* h16   = (float*)alloc((size_t)kN * kC * 4);
  float* hC    = (float*)alloc((size_t)kN * kC * 4);
  float* nei   = (float*)alloc((size_t)kN * kC * 4);
  float* lx    = (float*)alloc((size_t)kN * kC * 4);
  int*   yhat  = (int*)alloc((size_t)kN * 4);
  float* conf  = (float*)alloc((size_t)kE * 4);
  float* V     = (float*)alloc((size_t)kN * kK * 4);
  float* U     = (float*)alloc((size_t)kN * kK * 4);
  float* T     = (float*)alloc((size_t)kN * kK * 4);
  float* score = (float*)alloc((size_t)kE * 4);
  float* SS    = (float*)alloc((size_t)kE * 4);
  float* G     = (float*)alloc(64 * 64 * 4);
  float* Gi    = (float*)alloc(64 * 64 * 4);
  float* hTX   = (float*)alloc(kC * kK * 4);
  int* hist1   = (int*)alloc(4096 * 4);
  int* h2a     = (int*)alloc(4096 * 4);
  int* h2b     = (int*)alloc(4096 * 4);
  int* h3a     = (int*)alloc(256 * 4);
  int* h3b     = (int*)alloc(256 * 4);
  SelState* sel = (SelState*)alloc(sizeof(SelState));
  float* wsoft = (float*)alloc(4 * 4);
  int* cntR    = (int*)alloc((size_t)kN * 4);
  int* cntC    = (int*)alloc((size_t)kN * 4);
  int* fillR   = (int*)alloc((size_t)kN * 4);
  int* fillC   = (int*)alloc((size_t)kN * 4);
  int* startR  = (int*)alloc((size_t)(kN + 1) * 4);
  int* startC  = (int*)alloc((size_t)(kN + 1) * 4);
  int* eR      = (int*)alloc((size_t)kE * 4);
  int* eC      = (int*)alloc((size_t)kE * 4);
  float* P     = (float*)alloc((size_t)100 * 4096 * 4);
  float* Pbig  = (float*)alloc((size_t)4 * kN * kNH * 4);  // 41 MB split-K partials
  float* Px    = (float*)alloc((size_t)kN * kNH * 4);      // 10 MB x-GEMM partial

  const int eg  = (kE + 255) / 256;
  const int nkg = (kN * kK + 255) / 256;
  const int gwg = (kN + 3) / 4;

  // ---- CSR build (span via pointer-diff: alloc pads to 256B) ----
  {
    size_t csrSpan = (size_t)((char*)(fillC + kN) - (char*)cntR);
    (void)hipMemsetAsync(cntR, 0, csrSpan, stream);
  }
  csr_count<<<eg, 256, 0, stream>>>(row, col, cntR, cntC, kE);
  scan2<<<1, 1024, 0, stream>>>(cntR, cntC, startR, startC, kN);
  csr_fill<<<eg, 256, 0, stream>>>(row, col, startR, startC, fillR, fillC, eR, eC, kE);

  // ---- dense front-end ----
  gemm_skbf16<128><<<dim3(157, 2, 4), 256, 0, stream>>>(connect, lin_a_w, nullptr, Pbig,
                                                        kN, kN, 2500, kNH);
  gemm_skbf16<128><<<dim3(157, 2, 1), 256, 0, stream>>>(x, lin1_w, nullptr, Px,
                                                        kN, 500, 500, kNH);
  reduce_raw<<<(kN * kNH / 4 + 255) / 256, 256, 0, stream>>>(
      (const float4*)Pbig, (const float4*)Px, lin_a_b, lin1_b, (float4*)raw);
  gemm_rowdot<<<(kN * kC + 255) / 256, 256, 0, stream>>>(raw, lin2_w, lin2_b, h16, kN, kC, kNH);
  argmax16<<<(kN + 255) / 256, 256, 0, stream>>>(h16, yhat, kN);
  (void)hipMemsetAsync(nei, 0, (size_t)kN * kC * 4, stream);
  scatter_nei<<<eg, 256, 0, stream>>>(row, col, aw, yhat, nei, kE);
  norm_xn_h<<<(kN + 255) / 256, 256, 0, stream>>>(nei, h16, lin_n_w, lin_n_b, hC, kN);
  gemm_rowdot<<<(kN * kC + 255) / 256, 256, 0, stream>>>(hC, left_w, nullptr, lx, kN, kC, kC);
  softmax3<<<1, 1, 0, stream>>>(conf_p, wsoft);
  edge_conf<<<eg, 256, 0, stream>>>(row, col, lx, att_w, ci, wsoft, conf, kE);
  // V = raw @ v_w^T + v_b via MFMA (BN=64, final write w/ bias)
  gemm_skbf16<64><<<dim3(157, 1, 1), 256, 0, stream>>>(raw, v_w, v_b, V, kN, kNH, kNH, kK);

  // ---- U init ----
  gram_partial<<<100, 256, 0, stream>>>(V, V, P, kN, 64, 100);
  gram_reduce<<<16, 256, 0, stream>>>(P, G, 4096, 100);
  inverse64_spd<<<1, 256, 0, stream>>>(G, Gi, 1.0f, 0.0f);
  (void)hipMemsetAsync(T, 0, (size_t)kN * kK * 4, stream);
  spmm_gather<<<gwg, 256, 0, stream>>>(aw, startR, eR, col, V, T, kN);
  mul_right64<<<nkg, 256, 0, stream>>>(T, Gi, U, kN);

  for (int j = 0; j < 4; j++) {
    bool upd_u = ((j & 1) == 0);
    const float* Ma = upd_u ? U : V;
    const float* Mb = upd_u ? V : U;
    edge_score<<<eg, 256, 0, stream>>>(ew, row, col, Ma, Mb, score, hist1, kE);
    hist_pass1<<<eg, 256, 0, stream>>>(score, hist1, h2a, h2b, kE);
    select_scan<<<1, 256, 0, stream>>>(hist1, hist1, 4096, 1, sel);
    hist_pass2<<<eg, 256, 0, stream>>>(score, sel, h2a, h2b, h3a, h3b, kE);
    select_scan<<<1, 256, 0, stream>>>(h2a, h2b, 4096, 2, sel);
    hist_pass3<<<eg, 256, 0, stream>>>(score, sel, h3a, h3b, kE);
    select_scan<<<1, 256, 0, stream>>>(h3a, h3b, 256, 3, sel);
    mask_SS<<<eg, 256, 0, stream>>>(score, conf, sel, b_param, SS, kE);

    const float* Xcur = upd_u ? U : V;
    const float* Moth = upd_u ? V : U;
    gram_partial<<<100, 256, 0, stream>>>(Moth, Moth, P, kN, 64, 100);
    gram_reduce<<<16, 256, 0, stream>>>(P, G, 4096, 100);
    gram_partial<<<100, 256, 0, stream>>>(hC, Moth, P, kN, 16, 100);
    gram_reduce<<<4, 256, 0, stream>>>(P, hTX, 1024, 100);
    inverse64_spd<<<1, 256, 0, stream>>>(G, Gi, 1.1f, 1.0f);
    base_temp<<<nkg, 256, 0, stream>>>(Xcur, G, hC, hTX, T, kN);
    if (upd_u) spmm_gather<<<gwg, 256, 0, stream>>>(SS, startR, eR, col, V, T, kN);
    else       spmm_gather<<<gwg, 256, 0, stream>>>(SS, startC, eC, row, U, T, kN);
    mul_right64<<<nkg, 256, 0, stream>>>(T, Gi, upd_u ? U : V, kN);
  }

  gram_partial<<<100, 256, 0, stream>>>(hC, V, P, kN, 16, 100);
  gram_reduce<<<4, 256, 0, stream>>>(P, hTX, 1024, 100);
  final_out<<<(kN + 255) / 256, 256, 0, stream>>>(U, hTX, hC, Wm, out, kN);
}

// Round 6
// 2528.818 us; speedup vs baseline: 2.7186x; 1.7189x over previous
//
#include <hip/hip_runtime.h>
#include <cstddef>
#include <cstdint>

// Round 6:
//  GEMM v3: pre-split B to bf16 hi/lo; 2-term (A-hi only) for connect, 3-term
//    for x/V; BN=256 wave-quadrant tiling (32 MFMA / 12 ds_read per K-step);
//    XOR-swizzled LDS (2-way max = free).
//  Tail: base_temp+mul_right64 fused via Gp=G@Gi, Hp=EPS*hTX@Gi (inverse
//    epilogue); U/V ping-pong; 2-pass 16-bit exact radix select; spmm '='
//    (no T memsets) + unroll-4 + prebuilt other[]; softmax folded into edge_conf.

constexpr int kN  = 10000;
constexpr int kE  = 320000;
constexpr int kNH = 256;
constexpr int kC  = 16;
constexpr int kK  = 64;

struct SelState {
  int bin1[2]; int rem1[2];
  float thr_base;
};

typedef short bf16x8 __attribute__((ext_vector_type(8)));
typedef float f32x4 __attribute__((ext_vector_type(4)));
typedef ushort ushort8 __attribute__((ext_vector_type(8)));

__device__ __forceinline__ ushort f2bf(float x) {
  unsigned u = __float_as_uint(x);
  unsigned r = (u + 0x7fffu + ((u >> 16) & 1u)) >> 16;   // RNE
  return (ushort)r;
}
__device__ __forceinline__ float bf2f(ushort h) {
  return __uint_as_float((unsigned)h << 16);
}
// LDS swizzle for row-major [rows][32] ushort tiles (64B rows, 16B chunks):
// chunk ^= (row>>1)&3  -> b128 frag reads land 2 lanes/bank-quad (free).
__device__ __forceinline__ int swz(int row, int byteInRow) {
  int chunk = (byteInRow >> 4) ^ ((row >> 1) & 3);
  return row * 64 + (chunk << 4) + (byteInRow & 15);
}

// pre-split fp32 weight matrix [N2,K] -> bf16 hi/lo [N2,Kp], zero-padded
__global__ void split_bf(const float* __restrict__ B, ushort* __restrict__ hi,
                         ushort* __restrict__ lo, int N2, int K, int Kp)
{
  int t = blockIdx.x * 256 + threadIdx.x;
  if (t >= N2 * Kp) return;
  int r = t / Kp, c = t % Kp;
  float v = (c < K) ? B[(size_t)r * K + c] : 0.f;
  ushort h = f2bf(v);
  hi[t] = h;
  lo[t] = f2bf(v - bf2f(h));
}

// ===== MFMA GEMM: out(+slice) = A[M,K] @ B[N2=BN,K]^T ; B pre-split bf16 =====
// grid(ceil(M/64), 1, nsplit). ALO=1 adds the Alo*Bhi term (3-term split).
template<int BN, bool ALO>
__global__ __launch_bounds__(256) void gemm_v3(
    const float* __restrict__ A, const ushort* __restrict__ Bhg,
    const ushort* __restrict__ Blg, const float* __restrict__ bias,
    float* __restrict__ out, int M, int K, int Kp, int KR, int outStride)
{
  __shared__ __align__(16) char sAh[64 * 64];
  __shared__ __align__(16) char sAl[ALO ? 64 * 64 : 16];
  __shared__ __align__(16) char sBh[BN * 64];
  __shared__ __align__(16) char sBl[BN * 64];
  const int t = threadIdx.x;
  const int lane = t & 63, w = t >> 6;
  const int bm = blockIdx.x * 64;
  const int k0 = blockIdx.z * KR;
  const int kend = min(K, k0 + KR);
  out += (size_t)blockIdx.z * M * outStride;
  constexpr int WN = BN / 64;       // wave-cols (4 for BN=256, 1 for BN=64)
  constexpr int RB = WN;            // row frags per wave (64/WM/16)
  const int wc = (w % WN) * 64;
  const int wr = (w / WN) * (RB * 16);
  const int l15 = lane & 15;
  const int lByte = (lane >> 4) * 16;
  const int ar = t >> 2, ac = t & 3;     // A staging task: row, chunk

  f32x4 acc[RB][4] = {};
  for (int kt = k0; kt < kend; kt += 32) {
    { // stage A (64x32 fp32 -> bf16 hi[/lo]), one 16B chunk per thread
      int gr = bm + ar, gk = kt + ac * 8;
      float v[8];
      if (gr < M && gk + 8 <= kend) {
        float4 v0 = *reinterpret_cast<const float4*>(A + (size_t)gr * K + gk);
        float4 v1 = *reinterpret_cast<const float4*>(A + (size_t)gr * K + gk + 4);
        v[0] = v0.x; v[1] = v0.y; v[2] = v0.z; v[3] = v0.w;
        v[4] = v1.x; v[5] = v1.y; v[6] = v1.z; v[7] = v1.w;
      } else {
#pragma unroll
        for (int q = 0; q < 8; q++)
          v[q] = (gr < M && gk + q < kend) ? A[(size_t)gr * K + gk + q] : 0.f;
      }
      ushort8 h8, l8;
#pragma unroll
      for (int q = 0; q < 8; q++) {
        ushort h = f2bf(v[q]); h8[q] = h;
        if (ALO) l8[q] = f2bf(v[q] - bf2f(h));
      }
      *reinterpret_cast<ushort8*>(sAh + swz(ar, ac * 16)) = h8;
      if (ALO) *reinterpret_cast<ushort8*>(sAl + swz(ar, ac * 16)) = l8;
    }
    // stage B (BNx32 bf16 hi+lo), padded Kp: no guards needed
#pragma unroll
    for (int i2 = 0; i2 < BN / 64; i2++) {
      int idx = t + i2 * 256;
      int r = idx >> 2, c = idx & 3;
      size_t gb = (size_t)r * Kp + kt + c * 8;
      ushort8 hv = *reinterpret_cast<const ushort8*>(Bhg + gb);
      ushort8 lv = *reinterpret_cast<const ushort8*>(Blg + gb);
      *reinterpret_cast<ushort8*>(sBh + swz(r, c * 16)) = hv;
      *reinterpret_cast<ushort8*>(sBl + swz(r, c * 16)) = lv;
    }
    __syncthreads();
    bf16x8 bh[4], bl[4];
#pragma unroll
    for (int nb = 0; nb < 4; nb++) {
      int rr = wc + nb * 16 + l15;
      bh[nb] = *reinterpret_cast<const bf16x8*>(sBh + swz(rr, lByte));
      bl[nb] = *reinterpret_cast<const bf16x8*>(sBl + swz(rr, lByte));
    }
#pragma unroll
    for (int rb = 0; rb < RB; rb++) {
      int rr = wr + rb * 16 + l15;
      bf16x8 ah = *reinterpret_cast<const bf16x8*>(sAh + swz(rr, lByte));
#pragma unroll
      for (int nb = 0; nb < 4; nb++) {
        acc[rb][nb] = __builtin_amdgcn_mfma_f32_16x16x32_bf16(ah, bh[nb], acc[rb][nb], 0, 0, 0);
        acc[rb][nb] = __builtin_amdgcn_mfma_f32_16x16x32_bf16(ah, bl[nb], acc[rb][nb], 0, 0, 0);
      }
      if (ALO) {
        bf16x8 al = *reinterpret_cast<const bf16x8*>(sAl + swz(rr, lByte));
#pragma unroll
        for (int nb = 0; nb < 4; nb++)
          acc[rb][nb] = __builtin_amdgcn_mfma_f32_16x16x32_bf16(al, bh[nb], acc[rb][nb], 0, 0, 0);
      }
    }
    __syncthreads();
  }
#pragma unroll
  for (int rb = 0; rb < RB; rb++) {
#pragma unroll
    for (int nb = 0; nb < 4; nb++) {
      int colg = wc + nb * 16 + l15;
      float bv = bias ? bias[colg] : 0.f;
#pragma unroll
      for (int j = 0; j < 4; j++) {
        int rowg = bm + wr + rb * 16 + (lane >> 4) * 4 + j;
        if (rowg < M) out[(size_t)rowg * outStride + colg] = acc[rb][nb][j] + bv;
      }
    }
  }
}

// raw = relu(0.5*(sum5(Pa)+ba) + 0.5*(raw+b1))  (x-GEMM partial lives in raw)
__global__ void reduce_raw(const float4* __restrict__ Pa, const float4* px,
                           const float* __restrict__ ba, const float* __restrict__ b1,
                           float4* rawOut)
{
  int t = blockIdx.x * 256 + threadIdx.x;
  if (t >= kN * kNH / 4) return;
  const int sl = kN * kNH / 4;
  float4 s = Pa[t];
#pragma unroll
  for (int p = 1; p < 5; p++) {
    float4 q = Pa[t + (size_t)p * sl];
    s.x += q.x; s.y += q.y; s.z += q.z; s.w += q.w;
  }
  float4 pxv = px[t];
  int c4 = t & 63;
  float4 vba = reinterpret_cast<const float4*>(ba)[c4];
  float4 vb1 = reinterpret_cast<const float4*>(b1)[c4];
  float4 r;
  r.x = fmaxf(0.5f * (s.x + vba.x) + 0.5f * (pxv.x + vb1.x), 0.f);
  r.y = fmaxf(0.5f * (s.y + vba.y) + 0.5f * (pxv.y + vb1.y), 0.f);
  r.z = fmaxf(0.5f * (s.z + vba.z) + 0.5f * (pxv.z + vb1.z), 0.f);
  r.w = fmaxf(0.5f * (s.w + vba.w) + 0.5f * (pxv.w + vb1.w), 0.f);
  rawOut[t] = r;
}

__global__ void gemm_rowdot(const float* __restrict__ A, const float* __restrict__ Bw,
                            const float* __restrict__ bias, float* __restrict__ outm,
                            int M, int N2, int K2)
{
  int t = blockIdx.x * 256 + threadIdx.x;
  if (t >= M * N2) return;
  int i = t / N2, j = t % N2;
  const float4* a = reinterpret_cast<const float4*>(A + (size_t)i * K2);
  const float4* b = reinterpret_cast<const float4*>(Bw + (size_t)j * K2);
  float s = bias ? bias[j] : 0.f;
  int q4 = K2 >> 2;
  for (int q = 0; q < q4; q++) {
    float4 av = a[q], bv = b[q];
    s += av.x * bv.x + av.y * bv.y + av.z * bv.z + av.w * bv.w;
  }
  outm[t] = s;
}

__global__ void argmax16(const float* __restrict__ h, int* __restrict__ y, int n)
{
  int i = blockIdx.x * 256 + threadIdx.x;
  if (i >= n) return;
  const float* r = h + (size_t)i * 16;
  float m = r[0]; int a = 0;
#pragma unroll
  for (int j = 1; j < 16; j++) { float v = r[j]; if (v > m) { m = v; a = j; } }
  y[i] = a;
}

__global__ void scatter_nei(const int* __restrict__ row, const int* __restrict__ col,
                            const float* __restrict__ aw, const int* __restrict__ yhat,
                            float* nei, int E)
{
  int e = blockIdx.x * 256 + threadIdx.x;
  if (e >= E) return;
  atomicAdd(&nei[(size_t)row[e] * 16 + yhat[col[e]]], aw[e]);
}

__global__ void norm_xn_h(const float* __restrict__ nei, const float* __restrict__ h16,
                          const float* __restrict__ lnw, const float* __restrict__ lnb,
                          float* __restrict__ hc, int n)
{
  int i = blockIdx.x * 256 + threadIdx.x;
  if (i >= n) return;
  float nv[16]; float s = 0.f;
#pragma unroll
  for (int c = 0; c < 16; c++) { nv[c] = nei[(size_t)i * 16 + c]; s += nv[c]; }
  float inv = (s != 0.f) ? 1.f / s : 0.f;
#pragma unroll
  for (int j = 0; j < 16; j++) {
    float xn = lnb[j];
#pragma unroll
    for (int c = 0; c < 16; c++) xn += (nv[c] * inv) * lnw[j * 16 + c];
    xn = fmaxf(xn, 0.f);
    hc[(size_t)i * 16 + j] = 0.5f * h16[(size_t)i * 16 + j] + 0.5f * xn;
  }
}

// conf per edge; softmax(conf_param) computed in-kernel (was its own launch)
__global__ void edge_conf(const int* __restrict__ row, const int* __restrict__ col,
                          const float* __restrict__ lx, const float* __restrict__ attw,
                          const float* __restrict__ ci, const float* __restrict__ cp,
                          float* __restrict__ conf, int E)
{
  int e = blockIdx.x * 256 + threadIdx.x;
  if (e >= E) return;
  float p0 = cp[0], p1 = cp[1], p2 = cp[2];
  float m = fmaxf(p0, fmaxf(p1, p2));
  float e0 = expf(p0 - m), e1 = expf(p1 - m), e2 = expf(p2 - m);
  float inv = 1.f / (e0 + e1 + e2);
  float w0 = e0 * inv, w1 = e1 * inv, w2 = e2 * inv;
  const float* a = lx + (size_t)row[e] * 16;
  const float* b = lx + (size_t)col[e] * 16;
  float s = 0.f;
#pragma unroll
  for (int c = 0; c < 16; c++) s += fmaxf(a[c] + b[c], 0.f) * attw[c];
  float cf = 1.f / (1.f + expf(-s));
  conf[e] = cf * w0 + ci[e] * w1 + ci[(size_t)E + e] * w2;
}

// ---------------- CSR build ----------------
__global__ void csr_count(const int* __restrict__ row, const int* __restrict__ col,
                          int* cntR, int* cntC, int E)
{
  int e = blockIdx.x * 256 + threadIdx.x;
  if (e >= E) return;
  atomicAdd(&cntR[row[e]], 1);
  atomicAdd(&cntC[col[e]], 1);
}

__global__ __launch_bounds__(1024) void scan2(const int* __restrict__ cntR, const int* __restrict__ cntC,
                                              int* __restrict__ startR, int* __restrict__ startC, int n)
{
  __shared__ int part[1024];
  const int t = threadIdx.x;
  for (int pass = 0; pass < 2; ++pass) {
    const int* cnt = pass ? cntC : cntR;
    int* start = pass ? startC : startR;
    int base = t * 10;
    int loc[10]; int s = 0;
#pragma unroll
    for (int q = 0; q < 10; q++) { int idx = base + q; int v = (idx < n) ? cnt[idx] : 0; loc[q] = v; s += v; }
    part[t] = s;
    __syncthreads();
    for (int off = 1; off < 1024; off <<= 1) {
      int v = part[t];
      int u = (t >= off) ? part[t - off] : 0;
      __syncthreads();
      part[t] = v + u;
      __syncthreads();
    }
    int run = part[t] - s;
#pragma unroll
    for (int q = 0; q < 10; q++) { int idx = base + q; if (idx < n) start[idx] = run; run += loc[q]; }
    if (t == 1023) start[n] = part[1023];
    __syncthreads();
  }
}

// fill edge ids AND the gathered-node index (removes a dependent load in spmm)
__global__ void csr_fill(const int* __restrict__ row, const int* __restrict__ col,
                         const int* __restrict__ startR, const int* __restrict__ startC,
                         int* fillR, int* fillC, int* eR, int* eC,
                         int* othR, int* othC, int E)
{
  int e = blockIdx.x * 256 + threadIdx.x;
  if (e >= E) return;
  int r = row[e], c = col[e];
  int pr = startR[r] + atomicAdd(&fillR[r], 1);
  eR[pr] = e; othR[pr] = c;
  int pc = startC[c] + atomicAdd(&fillC[c], 1);
  eC[pc] = e; othC[pc] = r;
}

// T[i,:] = sum over segment i: vals[eids[p]] * Msrc[oth[p],:]  (wave/row, unroll-4)
__global__ void spmm_gather(const float* __restrict__ vals, const int* __restrict__ start,
                            const int* __restrict__ eids, const int* __restrict__ oth,
                            const float* __restrict__ Msrc, float* __restrict__ T, int n)
{
  int wid = blockIdx.x * 4 + (threadIdx.x >> 6);
  int lane = threadIdx.x & 63;
  if (wid >= n) return;
  int p = start[wid], pend = start[wid + 1];
  float acc = 0.f;
  for (; p + 4 <= pend; p += 4) {
    int e0 = eids[p], e1 = eids[p + 1], e2 = eids[p + 2], e3 = eids[p + 3];
    int o0 = oth[p], o1 = oth[p + 1], o2 = oth[p + 2], o3 = oth[p + 3];
    float m0 = Msrc[(size_t)o0 * 64 + lane];
    float m1 = Msrc[(size_t)o1 * 64 + lane];
    float m2 = Msrc[(size_t)o2 * 64 + lane];
    float m3 = Msrc[(size_t)o3 * 64 + lane];
    acc += vals[e0] * m0 + vals[e1] * m1 + vals[e2] * m2 + vals[e3] * m3;
  }
  for (; p < pend; ++p)
    acc += vals[eids[p]] * Msrc[(size_t)oth[p] * 64 + lane];
  T[(size_t)wid * 64 + lane] = acc;
}

// ---------------- two-stage gram ----------------
__global__ __launch_bounds__(256) void gram_partial(const float* __restrict__ A, const float* __restrict__ B,
                                                    float* __restrict__ P, int n, int Ka, int chunk)
{
  __shared__ float sA[8 * 64];
  __shared__ float sB[8 * 64];
  const int t = threadIdx.x;
  const int tpa = 256 / Ka;
  const int cpt = 64 / tpa;
  const int a  = t / tpa;
  const int c0 = (t % tpa) * cpt;
  float acc[16];
#pragma unroll
  for (int j = 0; j < 16; j++) acc[j] = 0.f;
  int r0 = blockIdx.x * chunk;
  int r1 = min(n, r0 + chunk);
  for (int rb = r0; rb < r1; rb += 8) {
    int nb = min(8, r1 - rb);
    for (int q = t; q < nb * Ka; q += 256) sA[(q / Ka) * 64 + (q % Ka)] = A[(size_t)(rb + q / Ka) * Ka + (q % Ka)];
    for (int q = t; q < nb * 64; q += 256) sB[q] = B[(size_t)rb * 64 + q];
    __syncthreads();
    for (int r = 0; r < nb; r++) {
      float av = sA[r * 64 + a];
      const float* sb = &sB[r * 64 + c0];
      if (cpt == 16) {
#pragma unroll
        for (int j = 0; j < 16; j++) acc[j] += av * sb[j];
      } else {
#pragma unroll
        for (int j = 0; j < 4; j++) acc[j] += av * sb[j];
      }
    }
    __syncthreads();
  }
  float* p = P + (size_t)blockIdx.x * Ka * 64 + a * 64 + c0;
  if (cpt == 16) {
#pragma unroll
    for (int j = 0; j < 16; j++) p[j] = acc[j];
  } else {
#pragma unroll
    for (int j = 0; j < 4; j++) p[j] = acc[j];
  }
}

__global__ void gram_reduce(const float* __restrict__ P, float* __restrict__ G, int cells, int parts)
{
  int c = blockIdx.x * 256 + threadIdx.x;
  if (c >= cells) return;
  float s = 0.f;
  for (int p = 0; p < parts; p++) s += P[(size_t)p * cells + c];
  G[c] = s;
}

// ---------- SPD inverse of (alpha*G + beta*I); epilogue: Gp=G@Gi, Hp=EPS*hTX@Gi
__global__ __launch_bounds__(256) void inverse64_spd(
    const float* __restrict__ G, float* __restrict__ Gi, float alpha, float beta,
    const float* __restrict__ hTX, float* __restrict__ Gp, float* __restrict__ Hp)
{
  __shared__ __align__(16) float A[64 * 132];
  __shared__ __align__(16) float prow[128];
  __shared__ float fcol[64];
  const int t = threadIdx.x;
  for (int q = t; q < 64 * 128; q += 256) {
    int r = q >> 7, c = q & 127;
    float v;
    if (c < 64) v = alpha * G[r * 64 + c] + ((c == r) ? beta : 0.f);
    else        v = (c - 64 == r) ? 1.f : 0.f;
    A[r * 132 + c] = v;
  }
  __syncthreads();
  const int i  = t >> 2;
  const int c0 = (t & 3) * 32;
  for (int k = 0; k < 64; k++) {
    if (t < 128) prow[t] = A[k * 132 + t];
    else if (t < 192) fcol[t - 128] = A[(t - 128) * 132 + k];
    __syncthreads();
    float pinv = 1.f / prow[k];
    float f = fcol[i];
    float4* Ar = reinterpret_cast<float4*>(&A[i * 132 + c0]);
    const float4* pr = reinterpret_cast<const float4*>(&prow[c0]);
    if (i == k) {
#pragma unroll
      for (int j = 0; j < 8; j++) {
        float4 p = pr[j];
        p.x *= pinv; p.y *= pinv; p.z *= pinv; p.w *= pinv;
        Ar[j] = p;
      }
    } else {
#pragma unroll
      for (int j = 0; j < 8; j++) {
        float4 p = pr[j]; float4 av = Ar[j];
        av.x -= f * (p.x * pinv); av.y -= f * (p.y * pinv);
        av.z -= f * (p.z * pinv); av.w -= f * (p.w * pinv);
        Ar[j] = av;
      }
    }
    __syncthreads();
  }
  for (int q = t; q < 4096; q += 256) Gi[q] = A[(q >> 6) * 132 + 64 + (q & 63)];
  if (Gp) {
    for (int q = t; q < 4096; q += 256) {
      int r = q >> 6, k = q & 63;
      float s = 0.f;
#pragma unroll 8
      for (int j = 0; j < 64; j++) s += G[r * 64 + j] * A[j * 132 + 64 + k];
      Gp[q] = s;
    }
    for (int q = t; q < 1024; q += 256) {
      int c = q >> 6, k = q & 63;
      float s = 0.f;
#pragma unroll 8
      for (int j = 0; j < 64; j++) s += hTX[c * 64 + j] * A[j * 132 + 64 + k];
      Hp[q] = 0.1f * s;  // EPS
    }
  }
}

// score[e] = ew[e] - dot64(Ma[row], Mb[col]); also zeroes the 3 radix hists
__global__ void edge_score(const float* __restrict__ ew, const int* __restrict__ row,
                           const int* __restrict__ col, const float* __restrict__ Ma,
                           const float* __restrict__ Mb, float* __restrict__ score,
                           int* __restrict__ hist1, int* __restrict__ h2a,
                           int* __restrict__ h2b, int E)
{
  int e = blockIdx.x * 256 + threadIdx.x;
  if (e < 65536) { hist1[e] = 0; h2a[e] = 0; h2b[e] = 0; }
  if (e >= E) return;
  const float4* a = reinterpret_cast<const float4*>(Ma + (size_t)row[e] * 64);
  const float4* b = reinterpret_cast<const float4*>(Mb + (size_t)col[e] * 64);
  float s = 0.f;
#pragma unroll
  for (int q = 0; q < 16; q++) {
    float4 av = a[q], bv = b[q];
    s += av.x * bv.x + av.y * bv.y + av.z * bv.z + av.w * bv.w;
  }
  score[e] = ew[e] - s;
}

// ---- exact 2-pass 16-bit radix selection on S = score^2 ----
__global__ void hist_pass1(const float* __restrict__ score, int* __restrict__ h, int E)
{
  int e = blockIdx.x * 256 + threadIdx.x;
  if (e >= E) return;
  float sc = score[e];
  unsigned u = __float_as_uint(sc * sc);
  atomicAdd(&h[u >> 16], 1);
}

__global__ void hist_pass2(const float* __restrict__ score, const SelState* __restrict__ sel,
                           int* __restrict__ h2a, int* __restrict__ h2b, int E)
{
  int e = blockIdx.x * 256 + threadIdx.x;
  if (e >= E) return;
  float sc = score[e];
  unsigned u = __float_as_uint(sc * sc);
  int top = (int)(u >> 16);
  if (top == sel->bin1[0]) atomicAdd(&h2a[u & 0xFFFF], 1);
  if (top == sel->bin1[1]) atomicAdd(&h2b[u & 0xFFFF], 1);
}

// stage 1: ranks {E/4, 3E/4} over hist1 (h0==h1); stage 2: rem over h2a/h2b -> thr
__global__ __launch_bounds__(256) void select_scan(
    const int* __restrict__ h0, const int* __restrict__ h1,
    int stage, SelState* sel)
{
  const int t = threadIdx.x;
  __shared__ int part[256];
  __shared__ int foundBin[2];
  __shared__ float qsh[2];
  const int per = 65536 / 256;
  for (int tgt = 0; tgt < 2; tgt++) {
    const int* H = tgt ? h1 : h0;
    int R = (stage == 1) ? (tgt ? (3 * kE / 4) : (kE / 4)) : sel->rem1[tgt];
    int lsum = 0;
    for (int b = 0; b < per; b++) lsum += H[t * per + b];
    part[t] = lsum;
    __syncthreads();
    for (int off = 1; off < 256; off <<= 1) {
      int v = part[t];
      int u = (t >= off) ? part[t - off] : 0;
      __syncthreads();
      part[t] = v + u;
      __syncthreads();
    }
    int cum = part[t] - lsum;
    int fb = -1, fr = 0;
    for (int b = 0; b < per; b++) {
      int c = H[t * per + b];
      if (R >= cum && R < cum + c) { fb = t * per + b; fr = R - cum; }
      cum += c;
    }
    if (fb >= 0) {
      foundBin[tgt] = fb;
      if (stage == 1) { sel->bin1[tgt] = fb; sel->rem1[tgt] = fr; }
    }
    __syncthreads();
    if (stage == 2 && t == 0) {
      unsigned u = ((unsigned)sel->bin1[tgt] << 16) | (unsigned)foundBin[tgt];
      qsh[tgt] = __uint_as_float(u);
    }
    __syncthreads();
  }
  if (stage == 2 && t == 0) {
    float q1 = qsh[0], q3 = qsh[1];
    sel->thr_base = q3 + 1.5f * (q3 - q1);
  }
}

__global__ void mask_SS(const float* __restrict__ score, const float* __restrict__ conf,
                        const SelState* __restrict__ sel, const float* __restrict__ bp,
                        float* __restrict__ SS, int E)
{
  int e = blockIdx.x * 256 + threadIdx.x;
  if (e >= E) return;
  float sc = score[e];
  float thr = sel->thr_base * conf[e];
  SS[e] = (sc * sc < thr) ? (sc + bp[0]) : 0.f;
}

// Out[i,k] = T[i,:]@Gi[:,k] (+ X[i,:]@Gp[:,k] + hc[i,:]@Hp[:,k])
// replaces base_temp+mul_right64 via (X@G + EPS h@hTX)@Gi = X@(G@Gi) + h@(EPS hTX@Gi)
__global__ void out_fused(const float* __restrict__ T, const float* __restrict__ Gi,
                          const float* __restrict__ X, const float* __restrict__ Gp,
                          const float* __restrict__ hc, const float* __restrict__ Hp,
                          float* __restrict__ Out, int n)
{
  int t = blockIdx.x * 256 + threadIdx.x;
  if (t >= n * 64) return;
  int i = t >> 6, k = t & 63;
  const float* ti = T + (size_t)i * 64;
  float s = 0.f;
#pragma unroll 8
  for (int j = 0; j < 64; j++) s += ti[j] * Gi[j * 64 + k];
  if (X) {
    const float* xi = X + (size_t)i * 64;
    float s2 = 0.f;
#pragma unroll 8
    for (int j = 0; j < 64; j++) s2 += xi[j] * Gp[j * 64 + k];
    s += s2;
    float s3 = 0.f;
#pragma unroll
    for (int c = 0; c < 16; c++) s3 += hc[(size_t)i * 16 + c] * Hp[c * 64 + k];
    s += s3;
  }
  Out[t] = s;
}

__global__ __launch_bounds__(256) void final_out(
    const float* __restrict__ Um, const float* __restrict__ hTV,
    const float* __restrict__ hc, const float* __restrict__ Wm,
    float* __restrict__ out, int n)
{
  __shared__ float sh[1024];
  __shared__ float sW[256];
  for (int q = threadIdx.x; q < 1024; q += 256) sh[q] = hTV[q];
  sW[threadIdx.x] = Wm[threadIdx.x & 255];
  __syncthreads();
  int i = blockIdx.x * 256 + threadIdx.x;
  if (i >= n) return;
  const float* u = Um + (size_t)i * 64;
  float pre[16];
#pragma unroll
  for (int c = 0; c < 16; c++) {
    float s = 0.f;
#pragma unroll
    for (int k = 0; k < 64; k++) s += u[k] * sh[c * 64 + k];
    pre[c] = 0.9f * s + 0.1f * hc[(size_t)i * 16 + c];
  }
#pragma unroll
  for (int j = 0; j < 16; j++) {
    float o = 0.f;
#pragma unroll
    for (int c = 0; c < 16; c++) o += pre[c] * sW[c * 16 + j];
    out[(size_t)i * 16 + j] = o;
  }
}

extern "C" void kernel_launch(void* const* d_in, const int* in_sizes, int n_in,
                              void* d_out, int out_size, void* d_ws, size_t ws_size,
                              hipStream_t stream)
{
  const float* x       = (const float*)d_in[0];
  const int*   eidx    = (const int*)d_in[1];
  const float* ew      = (const float*)d_in[2];
  const float* aw      = (const float*)d_in[3];
  const float* connect = (const float*)d_in[4];
  const float* ci      = (const float*)d_in[5];
  const float* lin1_w  = (const float*)d_in[6];
  const float* lin1_b  = (const float*)d_in[7];
  const float* lin2_w  = (const float*)d_in[8];
  const float* lin2_b  = (const float*)d_in[9];
  const float* lin_a_w = (const float*)d_in[10];
  const float* lin_a_b = (const float*)d_in[11];
  const float* lin_n_w = (const float*)d_in[12];
  const float* lin_n_b = (const float*)d_in[13];
  const float* left_w  = (const float*)d_in[14];
  const float* att_w   = (const float*)d_in[15];
  const float* v_w     = (const float*)d_in[16];
  const float* v_b     = (const float*)d_in[17];
  const float* Wm      = (const float*)d_in[18];
  const float* conf_p  = (const float*)d_in[19];
  const float* b_param = (const float*)d_in[20];
  const int* row = eidx;
  const int* col = eidx + kE;
  float* out = (float*)d_out;

  char* base = (char*)d_ws;
  size_t off = 0;
  auto alloc = [&](size_t bytes) -> void* {
    void* p = base + off;
    off += bytes;
    off = (off + 255) & ~(size_t)255;
    return p;
  };
  float* raw   = (float*)alloc((size_t)kN * kNH * 4);
  float* h16   = (float*)alloc((size_t)kN * kC * 4);
  float* hC    = (float*)alloc((size_t)kN * kC * 4);
  float* nei   = (float*)alloc((size_t)kN * kC * 4);
  float* lx    = (float*)alloc((size_t)kN * kC * 4);
  int*   yhat  = (int*)alloc((size_t)kN * 4);
  float* conf  = (float*)alloc((size_t)kE * 4);
  float* Va    = (float*)alloc((size_t)kN * kK * 4);
  float* Vb    = (float*)alloc((size_t)kN * kK * 4);
  float* Ua    = (float*)alloc((size_t)kN * kK * 4);
  float* Ub    = (float*)alloc((size_t)kN * kK * 4);
  float* T     = (float*)alloc((size_t)kN * kK * 4);
  float* score = (float*)alloc((size_t)kE * 4);
  float* SS    = (float*)alloc((size_t)kE * 4);
  float* G     = (float*)alloc(64 * 64 * 4);
  float* Gi    = (float*)alloc(64 * 64 * 4);
  float* Gp    = (float*)alloc(64 * 64 * 4);
  float* hTX   = (float*)alloc(kC * kK * 4);
  float* Hp    = (float*)alloc(kC * kK * 4);
  int* hist1   = (int*)alloc(65536 * 4);
  int* h2a     = (int*)alloc(65536 * 4);
  int* h2b     = (int*)alloc(65536 * 4);
  SelState* sel = (SelState*)alloc(sizeof(SelState));
  int* cntR    = (int*)alloc((size_t)kN * 4);
  int* cntC    = (int*)alloc((size_t)kN * 4);
  int* fillR   = (int*)alloc((size_t)kN * 4);
  int* fillC   = (int*)alloc((size_t)kN * 4);
  int* startR  = (int*)alloc((size_t)(kN + 1) * 4);
  int* startC  = (int*)alloc((size_t)(kN + 1) * 4);
  int* eR      = (int*)alloc((size_t)kE * 4);
  int* eC      = (int*)alloc((size_t)kE * 4);
  int* othR    = (int*)alloc((size_t)kE * 4);
  int* othC    = (int*)alloc((size_t)kE * 4);
  float* P     = (float*)alloc((size_t)100 * 4096 * 4);
  // pre-split B weights (bf16 hi/lo, K padded to mult of 32)
  const int KpC = 10016, KpX = 512, KpV = 256;
  ushort* BcH = (ushort*)alloc((size_t)256 * KpC * 2);
  ushort* BcL = (ushort*)alloc((size_t)256 * KpC * 2);
  ushort* BxH = (ushort*)alloc((size_t)256 * KpX * 2);
  ushort* BxL = (ushort*)alloc((size_t)256 * KpX * 2);
  ushort* BvH = (ushort*)alloc((size_t)64 * KpV * 2);
  ushort* BvL = (ushort*)alloc((size_t)64 * KpV * 2);
  float* Pbig  = (float*)alloc((size_t)5 * kN * kNH * 4);  // 51 MB split-K partials

  const int eg  = (kE + 255) / 256;
  const int nkg = (kN * kK + 255) / 256;
  const int gwg = (kN + 3) / 4;

  // ---- pre-split weights ----
  split_bf<<<(256 * KpC + 255) / 256, 256, 0, stream>>>(lin_a_w, BcH, BcL, 256, 10000, KpC);
  split_bf<<<(256 * KpX + 255) / 256, 256, 0, stream>>>(lin1_w, BxH, BxL, 256, 500, KpX);
  split_bf<<<(64 * KpV + 255) / 256, 256, 0, stream>>>(v_w, BvH, BvL, 64, 256, KpV);

  // ---- CSR build (zero span via pointer-diff: alloc pads to 256B) ----
  {
    size_t csrSpan = (size_t)((char*)(fillC + kN) - (char*)cntR);
    (void)hipMemsetAsync(cntR, 0, csrSpan, stream);
  }
  csr_count<<<eg, 256, 0, stream>>>(row, col, cntR, cntC, kE);
  scan2<<<1, 1024, 0, stream>>>(cntR, cntC, startR, startC, kN);
  csr_fill<<<eg, 256, 0, stream>>>(row, col, startR, startC, fillR, fillC, eR, eC, othR, othC, kE);

  // ---- dense front-end ----
  gemm_v3<256, false><<<dim3(157, 1, 5), 256, 0, stream>>>(
      connect, BcH, BcL, nullptr, Pbig, kN, 10000, KpC, 2016, kNH);
  gemm_v3<256, true><<<dim3(157, 1, 1), 256, 0, stream>>>(
      x, BxH, BxL, nullptr, raw, kN, 500, KpX, 512, kNH);
  reduce_raw<<<(kN * kNH / 4 + 255) / 256, 256, 0, stream>>>(
      (const float4*)Pbig, (const float4*)raw, lin_a_b, lin1_b, (float4*)raw);
  gemm_rowdot<<<(kN * kC + 255) / 256, 256, 0, stream>>>(raw, lin2_w, lin2_b, h16, kN, kC, kNH);
  argmax16<<<(kN + 255) / 256, 256, 0, stream>>>(h16, yhat, kN);
  (void)hipMemsetAsync(nei, 0, (size_t)kN * kC * 4, stream);
  scatter_nei<<<eg, 256, 0, stream>>>(row, col, aw, yhat, nei, kE);
  norm_xn_h<<<(kN + 255) / 256, 256, 0, stream>>>(nei, h16, lin_n_w, lin_n_b, hC, kN);
  gemm_rowdot<<<(kN * kC + 255) / 256, 256, 0, stream>>>(hC, left_w, nullptr, lx, kN, kC, kC);
  edge_conf<<<eg, 256, 0, stream>>>(row, col, lx, att_w, ci, conf_p, conf, kE);
  gemm_v3<64, true><<<dim3(157, 1, 1), 256, 0, stream>>>(
      raw, BvH, BvL, v_b, Va, kN, 256, KpV, 256, kK);

  float* Ucur = Ua; float* Unxt = Ub;
  float* Vcur = Va; float* Vnxt = Vb;

  // ---- U init: U = spmm(aw,row,V[col]) @ inv(V^T V) ----
  gram_partial<<<100, 256, 0, stream>>>(Vcur, Vcur, P, kN, 64, 100);
  gram_reduce<<<16, 256, 0, stream>>>(P, G, 4096, 100);
  inverse64_spd<<<1, 256, 0, stream>>>(G, Gi, 1.0f, 0.0f, nullptr, nullptr, nullptr);
  spmm_gather<<<gwg, 256, 0, stream>>>(aw, startR, eR, othR, Vcur, T, kN);
  out_fused<<<nkg, 256, 0, stream>>>(T, Gi, nullptr, nullptr, nullptr, nullptr, Ucur, kN);

  for (int j = 0; j < 4; j++) {
    bool upd_u = ((j & 1) == 0);
    const float* Ma = upd_u ? Ucur : Vcur;   // gathered by row
    const float* Mb = upd_u ? Vcur : Ucur;   // gathered by col
    edge_score<<<eg, 256, 0, stream>>>(ew, row, col, Ma, Mb, score, hist1, h2a, h2b, kE);
    hist_pass1<<<eg, 256, 0, stream>>>(score, hist1, kE);
    select_scan<<<1, 256, 0, stream>>>(hist1, hist1, 1, sel);
    hist_pass2<<<eg, 256, 0, stream>>>(score, sel, h2a, h2b, kE);
    select_scan<<<1, 256, 0, stream>>>(h2a, h2b, 2, sel);
    mask_SS<<<eg, 256, 0, stream>>>(score, conf, sel, b_param, SS, kE);

    const float* Xcur = upd_u ? Ucur : Vcur;
    const float* Moth = upd_u ? Vcur : Ucur;
    float* Xout = upd_u ? Unxt : Vnxt;
    gram_partial<<<100, 256, 0, stream>>>(Moth, Moth, P, kN, 64, 100);
    gram_reduce<<<16, 256, 0, stream>>>(P, G, 4096, 100);
    gram_partial<<<100, 256, 0, stream>>>(hC, Moth, P, kN, 16, 100);
    gram_reduce<<<4, 256, 0, stream>>>(P, hTX, 1024, 100);
    inverse64_spd<<<1, 256, 0, stream>>>(G, Gi, 1.1f, 1.0f, hTX, Gp, Hp);
    if (upd_u) spmm_gather<<<gwg, 256, 0, stream>>>(SS, startR, eR, othR, Vcur, T, kN);
    else       spmm_gather<<<gwg, 256, 0, stream>>>(SS, startC, eC, othC, Ucur, T, kN);
    out_fused<<<nkg, 256, 0, stream>>>(T, Gi, Xcur, Gp, hC, Hp, Xout, kN);
    if (upd_u) { float* tmp = Ucur; Ucur = Unxt; Unxt = tmp; }
    else       { float* tmp = Vcur; Vcur = Vnxt; Vnxt = tmp; }
  }

  gram_partial<<<100, 256, 0, stream>>>(hC, Vcur, P, kN, 16, 100);
  gram_reduce<<<4, 256, 0, stream>>>(P, hTX, 1024, 100);
  final_out<<<(kN + 255) / 256, 256, 0, stream>>>(Ucur, hTX, hC, Wm, out, kN);
}

// Round 7
// 2219.748 us; speedup vs baseline: 3.0971x; 1.1392x over previous
//
#include <hip/hip_runtime.h>
#include <cstddef>
#include <cstdint>

// Round 7: tail fusion round.
//  - edge_score builds hist1 (fused); hists zeroed by preceding out_fused.
//  - gram2_partial: V^TV + hC^TV from ONE staging pass (same summation order).
//  - gram_reduce2: both reductions in one launch.
//  - SS computed on-the-fly in spmm_gather (mask_SS deleted).
//  - h16+argmax fused (16-lane shfl, first-max tie-break).
//  - select_scan: 1024 threads, int4 loads.
//  - out_fused: 4 outputs/thread, float4 weight loads (same accum order).
//  - connect GEMM: split-K 6 for balance. No new precision changes.

constexpr int kN  = 10000;
constexpr int kE  = 320000;
constexpr int kNH = 256;
constexpr int kC  = 16;
constexpr int kK  = 64;

struct SelState {
  int bin1[2]; int rem1[2];
  float thr_base;
};

typedef short bf16x8 __attribute__((ext_vector_type(8)));
typedef float f32x4 __attribute__((ext_vector_type(4)));
typedef ushort ushort8 __attribute__((ext_vector_type(8)));

__device__ __forceinline__ ushort f2bf(float x) {
  unsigned u = __float_as_uint(x);
  unsigned r = (u + 0x7fffu + ((u >> 16) & 1u)) >> 16;   // RNE
  return (ushort)r;
}
__device__ __forceinline__ float bf2f(ushort h) {
  return __uint_as_float((unsigned)h << 16);
}
// LDS swizzle for row-major [rows][32] ushort tiles (64B rows, 16B chunks):
// chunk ^= (row>>1)&3 -> b128 frag reads 2 lanes/bank-quad (free). [R6: conflicts 3.8e7 -> 0]
__device__ __forceinline__ int swz(int row, int byteInRow) {
  int chunk = (byteInRow >> 4) ^ ((row >> 1) & 3);
  return row * 64 + (chunk << 4) + (byteInRow & 15);
}

// pre-split fp32 weight matrix [N2,K] -> bf16 hi/lo [N2,Kp], zero-padded
__global__ void split_bf(const float* __restrict__ B, ushort* __restrict__ hi,
                         ushort* __restrict__ lo, int N2, int K, int Kp)
{
  int t = blockIdx.x * 256 + threadIdx.x;
  if (t >= N2 * Kp) return;
  int r = t / Kp, c = t % Kp;
  float v = (c < K) ? B[(size_t)r * K + c] : 0.f;
  ushort h = f2bf(v);
  hi[t] = h;
  lo[t] = f2bf(v - bf2f(h));
}

// ===== MFMA GEMM: out(+slice) = A[M,K] @ B[N2=BN,K]^T ; B pre-split bf16 =====
template<int BN, bool ALO>
__global__ __launch_bounds__(256) void gemm_v3(
    const float* __restrict__ A, const ushort* __restrict__ Bhg,
    const ushort* __restrict__ Blg, const float* __restrict__ bias,
    float* __restrict__ out, int M, int K, int Kp, int KR, int outStride)
{
  __shared__ __align__(16) char sAh[64 * 64];
  __shared__ __align__(16) char sAl[ALO ? 64 * 64 : 16];
  __shared__ __align__(16) char sBh[BN * 64];
  __shared__ __align__(16) char sBl[BN * 64];
  const int t = threadIdx.x;
  const int lane = t & 63, w = t >> 6;
  const int bm = blockIdx.x * 64;
  const int k0 = blockIdx.z * KR;
  const int kend = min(K, k0 + KR);
  out += (size_t)blockIdx.z * M * outStride;
  constexpr int WN = BN / 64;
  constexpr int RB = WN;
  const int wc = (w % WN) * 64;
  const int wr = (w / WN) * (RB * 16);
  const int l15 = lane & 15;
  const int lByte = (lane >> 4) * 16;
  const int ar = t >> 2, ac = t & 3;

  f32x4 acc[RB][4] = {};
  for (int kt = k0; kt < kend; kt += 32) {
    { // stage A (64x32 fp32 -> bf16 hi[/lo])
      int gr = bm + ar, gk = kt + ac * 8;
      float v[8];
      if (gr < M && gk + 8 <= kend) {
        float4 v0 = *reinterpret_cast<const float4*>(A + (size_t)gr * K + gk);
        float4 v1 = *reinterpret_cast<const float4*>(A + (size_t)gr * K + gk + 4);
        v[0] = v0.x; v[1] = v0.y; v[2] = v0.z; v[3] = v0.w;
        v[4] = v1.x; v[5] = v1.y; v[6] = v1.z; v[7] = v1.w;
      } else {
#pragma unroll
        for (int q = 0; q < 8; q++)
          v[q] = (gr < M && gk + q < kend) ? A[(size_t)gr * K + gk + q] : 0.f;
      }
      ushort8 h8, l8;
#pragma unroll
      for (int q = 0; q < 8; q++) {
        ushort h = f2bf(v[q]); h8[q] = h;
        if (ALO) l8[q] = f2bf(v[q] - bf2f(h));
      }
      *reinterpret_cast<ushort8*>(sAh + swz(ar, ac * 16)) = h8;
      if (ALO) *reinterpret_cast<ushort8*>(sAl + swz(ar, ac * 16)) = l8;
    }
#pragma unroll
    for (int i2 = 0; i2 < BN / 64; i2++) {
      int idx = t + i2 * 256;
      int r = idx >> 2, c = idx & 3;
      size_t gb = (size_t)r * Kp + kt + c * 8;
      ushort8 hv = *reinterpret_cast<const ushort8*>(Bhg + gb);
      ushort8 lv = *reinterpret_cast<const ushort8*>(Blg + gb);
      *reinterpret_cast<ushort8*>(sBh + swz(r, c * 16)) = hv;
      *reinterpret_cast<ushort8*>(sBl + swz(r, c * 16)) = lv;
    }
    __syncthreads();
    bf16x8 bh[4], bl[4];
#pragma unroll
    for (int nb = 0; nb < 4; nb++) {
      int rr = wc + nb * 16 + l15;
      bh[nb] = *reinterpret_cast<const bf16x8*>(sBh + swz(rr, lByte));
      bl[nb] = *reinterpret_cast<const bf16x8*>(sBl + swz(rr, lByte));
    }
#pragma unroll
    for (int rb = 0; rb < RB; rb++) {
      int rr = wr + rb * 16 + l15;
      bf16x8 ah = *reinterpret_cast<const bf16x8*>(sAh + swz(rr, lByte));
#pragma unroll
      for (int nb = 0; nb < 4; nb++) {
        acc[rb][nb] = __builtin_amdgcn_mfma_f32_16x16x32_bf16(ah, bh[nb], acc[rb][nb], 0, 0, 0);
        acc[rb][nb] = __builtin_amdgcn_mfma_f32_16x16x32_bf16(ah, bl[nb], acc[rb][nb], 0, 0, 0);
      }
      if (ALO) {
        bf16x8 al = *reinterpret_cast<const bf16x8*>(sAl + swz(rr, lByte));
#pragma unroll
        for (int nb = 0; nb < 4; nb++)
          acc[rb][nb] = __builtin_amdgcn_mfma_f32_16x16x32_bf16(al, bh[nb], acc[rb][nb], 0, 0, 0);
      }
    }
    __syncthreads();
  }
#pragma unroll
  for (int rb = 0; rb < RB; rb++) {
#pragma unroll
    for (int nb = 0; nb < 4; nb++) {
      int colg = wc + nb * 16 + l15;
      float bv = bias ? bias[colg] : 0.f;
#pragma unroll
      for (int j = 0; j < 4; j++) {
        int rowg = bm + wr + rb * 16 + (lane >> 4) * 4 + j;
        if (rowg < M) out[(size_t)rowg * outStride + colg] = acc[rb][nb][j] + bv;
      }
    }
  }
}

// raw = relu(0.5*(sum6(Pa)+ba) + 0.5*(raw+b1))
__global__ void reduce_raw(const float4* __restrict__ Pa, const float4* px,
                           const float* __restrict__ ba, const float* __restrict__ b1,
                           float4* rawOut)
{
  int t = blockIdx.x * 256 + threadIdx.x;
  if (t >= kN * kNH / 4) return;
  const int sl = kN * kNH / 4;
  float4 s = Pa[t];
#pragma unroll
  for (int p = 1; p < 6; p++) {
    float4 q = Pa[t + (size_t)p * sl];
    s.x += q.x; s.y += q.y; s.z += q.z; s.w += q.w;
  }
  float4 pxv = px[t];
  int c4 = t & 63;
  float4 vba = reinterpret_cast<const float4*>(ba)[c4];
  float4 vb1 = reinterpret_cast<const float4*>(b1)[c4];
  float4 r;
  r.x = fmaxf(0.5f * (s.x + vba.x) + 0.5f * (pxv.x + vb1.x), 0.f);
  r.y = fmaxf(0.5f * (s.y + vba.y) + 0.5f * (pxv.y + vb1.y), 0.f);
  r.z = fmaxf(0.5f * (s.z + vba.z) + 0.5f * (pxv.z + vb1.z), 0.f);
  r.w = fmaxf(0.5f * (s.w + vba.w) + 0.5f * (pxv.w + vb1.w), 0.f);
  rawOut[t] = r;
}

// h16 = raw @ lin2_w^T + b; yhat = argmax (first-max tie-break), fused
__global__ void h16_argmax(const float* __restrict__ raw, const float* __restrict__ w2,
                           const float* __restrict__ b2, float* __restrict__ h16,
                           int* __restrict__ yhat, int n)
{
  int t = blockIdx.x * 256 + threadIdx.x;
  if (t >= n * 16) return;
  int i = t >> 4, j = t & 15;
  const float4* a = reinterpret_cast<const float4*>(raw + (size_t)i * 256);
  const float4* b = reinterpret_cast<const float4*>(w2 + (size_t)j * 256);
  float s = b2[j];
#pragma unroll 8
  for (int q = 0; q < 64; q++) {
    float4 av = a[q], bv = b[q];
    s += av.x * bv.x + av.y * bv.y + av.z * bv.z + av.w * bv.w;
  }
  h16[t] = s;
  float m = s; int am = j;
#pragma unroll
  for (int off = 1; off < 16; off <<= 1) {
    float om = __shfl_xor(m, off);
    int oa = __shfl_xor(am, off);
    if (om > m || (om == m && oa < am)) { m = om; am = oa; }
  }
  if (j == 0) yhat[i] = am;
}

__global__ void scatter_nei(const int* __restrict__ row, const int* __restrict__ col,
                            const float* __restrict__ aw, const int* __restrict__ yhat,
                            float* nei, int E)
{
  int e = blockIdx.x * 256 + threadIdx.x;
  if (e >= E) return;
  atomicAdd(&nei[(size_t)row[e] * 16 + yhat[col[e]]], aw[e]);
}

__global__ void norm_xn_h(const float* __restrict__ nei, const float* __restrict__ h16,
                          const float* __restrict__ lnw, const float* __restrict__ lnb,
                          float* __restrict__ hc, int n)
{
  int i = blockIdx.x * 256 + threadIdx.x;
  if (i >= n) return;
  float nv[16]; float s = 0.f;
#pragma unroll
  for (int c = 0; c < 16; c++) { nv[c] = nei[(size_t)i * 16 + c]; s += nv[c]; }
  float inv = (s != 0.f) ? 1.f / s : 0.f;
#pragma unroll
  for (int j = 0; j < 16; j++) {
    float xn = lnb[j];
#pragma unroll
    for (int c = 0; c < 16; c++) xn += (nv[c] * inv) * lnw[j * 16 + c];
    xn = fmaxf(xn, 0.f);
    hc[(size_t)i * 16 + j] = 0.5f * h16[(size_t)i * 16 + j] + 0.5f * xn;
  }
}

__global__ void gemm_rowdot(const float* __restrict__ A, const float* __restrict__ Bw,
                            const float* __restrict__ bias, float* __restrict__ outm,
                            int M, int N2, int K2)
{
  int t = blockIdx.x * 256 + threadIdx.x;
  if (t >= M * N2) return;
  int i = t / N2, j = t % N2;
  const float4* a = reinterpret_cast<const float4*>(A + (size_t)i * K2);
  const float4* b = reinterpret_cast<const float4*>(Bw + (size_t)j * K2);
  float s = bias ? bias[j] : 0.f;
  int q4 = K2 >> 2;
  for (int q = 0; q < q4; q++) {
    float4 av = a[q], bv = b[q];
    s += av.x * bv.x + av.y * bv.y + av.z * bv.z + av.w * bv.w;
  }
  outm[t] = s;
}

__global__ void edge_conf(const int* __restrict__ row, const int* __restrict__ col,
                          const float* __restrict__ lx, const float* __restrict__ attw,
                          const float* __restrict__ ci, const float* __restrict__ cp,
                          float* __restrict__ conf, int E)
{
  int e = blockIdx.x * 256 + threadIdx.x;
  if (e >= E) return;
  float p0 = cp[0], p1 = cp[1], p2 = cp[2];
  float m = fmaxf(p0, fmaxf(p1, p2));
  float e0 = expf(p0 - m), e1 = expf(p1 - m), e2 = expf(p2 - m);
  float inv = 1.f / (e0 + e1 + e2);
  float w0 = e0 * inv, w1 = e1 * inv, w2 = e2 * inv;
  const float* a = lx + (size_t)row[e] * 16;
  const float* b = lx + (size_t)col[e] * 16;
  float s = 0.f;
#pragma unroll
  for (int c = 0; c < 16; c++) s += fmaxf(a[c] + b[c], 0.f) * attw[c];
  float cf = 1.f / (1.f + expf(-s));
  conf[e] = cf * w0 + ci[e] * w1 + ci[(size_t)E + e] * w2;
}

// ---------------- CSR build ----------------
__global__ void csr_count(const int* __restrict__ row, const int* __restrict__ col,
                          int* cntR, int* cntC, int E)
{
  int e = blockIdx.x * 256 + threadIdx.x;
  if (e >= E) return;
  atomicAdd(&cntR[row[e]], 1);
  atomicAdd(&cntC[col[e]], 1);
}

__global__ __launch_bounds__(1024) void scan2(const int* __restrict__ cntR, const int* __restrict__ cntC,
                                              int* __restrict__ startR, int* __restrict__ startC, int n)
{
  __shared__ int part[1024];
  const int t = threadIdx.x;
  for (int pass = 0; pass < 2; ++pass) {
    const int* cnt = pass ? cntC : cntR;
    int* start = pass ? startC : startR;
    int base = t * 10;
    int loc[10]; int s = 0;
#pragma unroll
    for (int q = 0; q < 10; q++) { int idx = base + q; int v = (idx < n) ? cnt[idx] : 0; loc[q] = v; s += v; }
    part[t] = s;
    __syncthreads();
    for (int off = 1; off < 1024; off <<= 1) {
      int v = part[t];
      int u = (t >= off) ? part[t - off] : 0;
      __syncthreads();
      part[t] = v + u;
      __syncthreads();
    }
    int run = part[t] - s;
#pragma unroll
    for (int q = 0; q < 10; q++) { int idx = base + q; if (idx < n) start[idx] = run; run += loc[q]; }
    if (t == 1023) start[n] = part[1023];
    __syncthreads();
  }
}

__global__ void csr_fill(const int* __restrict__ row, const int* __restrict__ col,
                         const int* __restrict__ startR, const int* __restrict__ startC,
                         int* fillR, int* fillC, int* eR, int* eC,
                         int* othR, int* othC, int E)
{
  int e = blockIdx.x * 256 + threadIdx.x;
  if (e >= E) return;
  int r = row[e], c = col[e];
  int pr = startR[r] + atomicAdd(&fillR[r], 1);
  eR[pr] = e; othR[pr] = c;
  int pc = startC[c] + atomicAdd(&fillC[c], 1);
  eC[pc] = e; othC[pc] = r;
}

// T[i,:] = sum over segment: val(e) * Msrc[oth[p],:]  (wave/row, unroll-4)
// val(e) = vals[e] if vals, else SS computed on the fly from score/conf/sel/bp.
__global__ void spmm_gather(const float* __restrict__ vals, const float* __restrict__ score,
                            const float* __restrict__ conf, const SelState* __restrict__ sel,
                            const float* __restrict__ bp, const int* __restrict__ start,
                            const int* __restrict__ eids, const int* __restrict__ oth,
                            const float* __restrict__ Msrc, float* __restrict__ T, int n)
{
  int wid = blockIdx.x * 4 + (threadIdx.x >> 6);
  int lane = threadIdx.x & 63;
  if (wid >= n) return;
  float tb = 0.f, bp0 = 0.f;
  if (!vals) { tb = sel->thr_base; bp0 = bp[0]; }
  auto val = [&](int e) -> float {
    if (vals) return vals[e];
    float sc = score[e];
    return (sc * sc < tb * conf[e]) ? (sc + bp0) : 0.f;
  };
  int p = start[wid], pend = start[wid + 1];
  float acc = 0.f;
  for (; p + 4 <= pend; p += 4) {
    int e0 = eids[p], e1 = eids[p + 1], e2 = eids[p + 2], e3 = eids[p + 3];
    int o0 = oth[p], o1 = oth[p + 1], o2 = oth[p + 2], o3 = oth[p + 3];
    float m0 = Msrc[(size_t)o0 * 64 + lane];
    float m1 = Msrc[(size_t)o1 * 64 + lane];
    float m2 = Msrc[(size_t)o2 * 64 + lane];
    float m3 = Msrc[(size_t)o3 * 64 + lane];
    acc += val(e0) * m0 + val(e1) * m1 + val(e2) * m2 + val(e3) * m3;
  }
  for (; p < pend; ++p)
    acc += val(eids[p]) * Msrc[(size_t)oth[p] * 64 + lane];
  T[(size_t)wid * 64 + lane] = acc;
}

// ---- fused gram: P1 = Moth^T Moth (64x64) and P2 = hC^T Moth (16x64), one staging pass
__global__ __launch_bounds__(256) void gram2_partial(
    const float* __restrict__ Moth, const float* __restrict__ hc,
    float* __restrict__ P, int n, int chunk)
{
  __shared__ float sM[8 * 64];
  __shared__ float sH[8 * 16];
  const int t = threadIdx.x;
  const int aG = t >> 2, cG0 = (t & 3) * 16;    // G mapping (Ka=64): identical to R6
  const int aH = t >> 4, cH0 = (t & 15) * 4;    // H mapping (Ka=16): identical to R6
  float accG[16];
  float accH[4];
#pragma unroll
  for (int j = 0; j < 16; j++) accG[j] = 0.f;
#pragma unroll
  for (int j = 0; j < 4; j++) accH[j] = 0.f;
  int r0 = blockIdx.x * chunk;
  int r1 = min(n, r0 + chunk);
  for (int rb = r0; rb < r1; rb += 8) {
    int nb = min(8, r1 - rb);
    for (int q = t; q < nb * 64; q += 256) sM[q] = Moth[(size_t)rb * 64 + q];
    for (int q = t; q < nb * 16; q += 256) sH[q] = hc[(size_t)rb * 16 + q];
    __syncthreads();
    for (int r = 0; r < nb; r++) {
      float avG = sM[r * 64 + aG];
      const float* sbG = &sM[r * 64 + cG0];
#pragma unroll
      for (int j = 0; j < 16; j++) accG[j] += avG * sbG[j];
      float avH = sH[r * 16 + aH];
      const float* sbH = &sM[r * 64 + cH0];
#pragma unroll
      for (int j = 0; j < 4; j++) accH[j] += avH * sbH[j];
    }
    __syncthreads();
  }
  float* p1 = P + (size_t)blockIdx.x * 5120 + aG * 64 + cG0;
#pragma unroll
  for (int j = 0; j < 16; j++) p1[j] = accG[j];
  float* p2 = P + (size_t)blockIdx.x * 5120 + 4096 + aH * 64 + cH0;
#pragma unroll
  for (int j = 0; j < 4; j++) p2[j] = accH[j];
}

// reduce both: G (4096 cells) and hTX (1024 cells), parts stride 5120
__global__ void gram_reduce2(const float* __restrict__ P, float* __restrict__ G,
                             float* __restrict__ hTX, int parts)
{
  int c = blockIdx.x * 256 + threadIdx.x;
  if (c >= 5120) return;
  float s = 0.f;
  for (int p = 0; p < parts; p++) s += P[(size_t)p * 5120 + c];
  if (c < 4096) G[c] = s;
  else hTX[c - 4096] = s;
}

// ---------- SPD inverse of (alpha*G + beta*I); epilogue: Gp=G@Gi, Hp=EPS*hTX@Gi
__global__ __launch_bounds__(256) void inverse64_spd(
    const float* __restrict__ G, float* __restrict__ Gi, float alpha, float beta,
    const float* __restrict__ hTX, float* __restrict__ Gp, float* __restrict__ Hp)
{
  __shared__ __align__(16) float A[64 * 132];
  __shared__ __align__(16) float prow[128];
  __shared__ float fcol[64];
  const int t = threadIdx.x;
  for (int q = t; q < 64 * 128; q += 256) {
    int r = q >> 7, c = q & 127;
    float v;
    if (c < 64) v = alpha * G[r * 64 + c] + ((c == r) ? beta : 0.f);
    else        v = (c - 64 == r) ? 1.f : 0.f;
    A[r * 132 + c] = v;
  }
  __syncthreads();
  const int i  = t >> 2;
  const int c0 = (t & 3) * 32;
  for (int k = 0; k < 64; k++) {
    if (t < 128) prow[t] = A[k * 132 + t];
    else if (t < 192) fcol[t - 128] = A[(t - 128) * 132 + k];
    __syncthreads();
    float pinv = 1.f / prow[k];
    float f = fcol[i];
    float4* Ar = reinterpret_cast<float4*>(&A[i * 132 + c0]);
    const float4* pr = reinterpret_cast<const float4*>(&prow[c0]);
    if (i == k) {
#pragma unroll
      for (int j = 0; j < 8; j++) {
        float4 p = pr[j];
        p.x *= pinv; p.y *= pinv; p.z *= pinv; p.w *= pinv;
        Ar[j] = p;
      }
    } else {
#pragma unroll
      for (int j = 0; j < 8; j++) {
        float4 p = pr[j]; float4 av = Ar[j];
        av.x -= f * (p.x * pinv); av.y -= f * (p.y * pinv);
        av.z -= f * (p.z * pinv); av.w -= f * (p.w * pinv);
        Ar[j] = av;
      }
    }
    __syncthreads();
  }
  for (int q = t; q < 4096; q += 256) Gi[q] = A[(q >> 6) * 132 + 64 + (q & 63)];
  if (Gp) {
    for (int q = t; q < 4096; q += 256) {
      int r = q >> 6, k = q & 63;
      float s = 0.f;
#pragma unroll 8
      for (int j = 0; j < 64; j++) s += G[r * 64 + j] * A[j * 132 + 64 + k];
      Gp[q] = s;
    }
    for (int q = t; q < 1024; q += 256) {
      int c = q >> 6, k = q & 63;
      float s = 0.f;
#pragma unroll 8
      for (int j = 0; j < 64; j++) s += hTX[c * 64 + j] * A[j * 132 + 64 + k];
      Hp[q] = 0.1f * s;  // EPS
    }
  }
}

// score[e] = ew[e] - dot64(Ma[row], Mb[col]); builds hist1 (zeroed by prior out_fused)
__global__ void edge_score(const float* __restrict__ ew, const int* __restrict__ row,
                           const int* __restrict__ col, const float* __restrict__ Ma,
                           const float* __restrict__ Mb, float* __restrict__ score,
                           int* __restrict__ hist1, int E)
{
  int e = blockIdx.x * 256 + threadIdx.x;
  if (e >= E) return;
  const float4* a = reinterpret_cast<const float4*>(Ma + (size_t)row[e] * 64);
  const float4* b = reinterpret_cast<const float4*>(Mb + (size_t)col[e] * 64);
  float s = 0.f;
#pragma unroll
  for (int q = 0; q < 16; q++) {
    float4 av = a[q], bv = b[q];
    s += av.x * bv.x + av.y * bv.y + av.z * bv.z + av.w * bv.w;
  }
  float sc = ew[e] - s;
  score[e] = sc;
  unsigned u = __float_as_uint(sc * sc);
  atomicAdd(&hist1[u >> 16], 1);
}

__global__ void hist_pass2(const float* __restrict__ score, const SelState* __restrict__ sel,
                           int* __restrict__ h2a, int* __restrict__ h2b, int E)
{
  int e = blockIdx.x * 256 + threadIdx.x;
  if (e >= E) return;
  float sc = score[e];
  unsigned u = __float_as_uint(sc * sc);
  int top = (int)(u >> 16);
  if (top == sel->bin1[0]) atomicAdd(&h2a[u & 0xFFFF], 1);
  if (top == sel->bin1[1]) atomicAdd(&h2b[u & 0xFFFF], 1);
}

// stage 1: ranks {E/4, 3E/4} over hist1; stage 2: rem over h2a/h2b -> thr
__global__ __launch_bounds__(1024) void select_scan(
    const int* __restrict__ h0, const int* __restrict__ h1,
    int stage, SelState* sel)
{
  const int t = threadIdx.x;
  __shared__ int part[1024];
  __shared__ int foundBin[2];
  __shared__ float qsh[2];
  const int per = 64;  // 65536 / 1024
  for (int tgt = 0; tgt < 2; tgt++) {
    const int* H = tgt ? h1 : h0;
    const int4* H4 = reinterpret_cast<const int4*>(H + t * per);
    int R = (stage == 1) ? (tgt ? (3 * kE / 4) : (kE / 4)) : sel->rem1[tgt];
    int lsum = 0;
#pragma unroll
    for (int b = 0; b < 16; b++) {
      int4 v = H4[b];
      lsum += v.x + v.y + v.z + v.w;
    }
    part[t] = lsum;
    __syncthreads();
    for (int off = 1; off < 1024; off <<= 1) {
      int v = part[t];
      int u = (t >= off) ? part[t - off] : 0;
      __syncthreads();
      part[t] = v + u;
      __syncthreads();
    }
    int cum = part[t] - lsum;
    int fb = -1, fr = 0;
#pragma unroll
    for (int b = 0; b < 16; b++) {
      int4 v = H4[b];
      int c0 = v.x, c1 = v.y, c2 = v.z, c3 = v.w;
      int bb = t * per + b * 4;
      if (R >= cum && R < cum + c0) { fb = bb; fr = R - cum; }
      cum += c0;
      if (fb < 0 && R >= cum && R < cum + c1) { fb = bb + 1; fr = R - cum; }
      cum += c1;
      if (fb < 0 && R >= cum && R < cum + c2) { fb = bb + 2; fr = R - cum; }
      cum += c2;
      if (fb < 0 && R >= cum && R < cum + c3) { fb = bb + 3; fr = R - cum; }
      cum += c3;
    }
    if (fb >= 0) {
      foundBin[tgt] = fb;
      if (stage == 1) { sel->bin1[tgt] = fb; sel->rem1[tgt] = fr; }
    }
    __syncthreads();
    if (stage == 2 && t == 0) {
      unsigned u = ((unsigned)sel->bin1[tgt] << 16) | (unsigned)foundBin[tgt];
      qsh[tgt] = __uint_as_float(u);
    }
    __syncthreads();
  }
  if (stage == 2 && t == 0) {
    float q1 = qsh[0], q3 = qsh[1];
    sel->thr_base = q3 + 1.5f * (q3 - q1);
  }
}

// Out[i,k4..k4+3]: T@Gi (+X@Gp + hc@Hp). 4 outputs/thread, float4 weight loads,
// per-output accumulation order identical to R6. Also zeroes the radix hists
// for the NEXT iteration's edge_score (stream-ordered).
__global__ void out_fused(const float* __restrict__ T, const float* __restrict__ Gi,
                          const float* __restrict__ X, const float* __restrict__ Gp,
                          const float* __restrict__ hc, const float* __restrict__ Hp,
                          float* __restrict__ Out, int n,
                          int* __restrict__ hist1, int* __restrict__ h2a,
                          int* __restrict__ h2b)
{
  int t = blockIdx.x * 256 + threadIdx.x;
  if (t < 65536) { hist1[t] = 0; h2a[t] = 0; h2b[t] = 0; }
  if (t >= n * 16) return;
  int i = t >> 4, kq = t & 15;
  const float* ti = T + (size_t)i * 64;
  const float4* G4 = reinterpret_cast<const float4*>(Gi);
  float4 s = make_float4(0.f, 0.f, 0.f, 0.f);
#pragma unroll 8
  for (int j = 0; j < 64; j++) {
    float tv = ti[j];
    float4 g = G4[j * 16 + kq];
    s.x += tv * g.x; s.y += tv * g.y; s.z += tv * g.z; s.w += tv * g.w;
  }
  if (X) {
    const float* xi = X + (size_t)i * 64;
    const float4* Gp4 = reinterpret_cast<const float4*>(Gp);
    float4 s2 = make_float4(0.f, 0.f, 0.f, 0.f);
#pragma unroll 8
    for (int j = 0; j < 64; j++) {
      float xv = xi[j];
      float4 g = Gp4[j * 16 + kq];
      s2.x += xv * g.x; s2.y += xv * g.y; s2.z += xv * g.z; s2.w += xv * g.w;
    }
    s.x += s2.x; s.y += s2.y; s.z += s2.z; s.w += s2.w;
    const float4* Hp4 = reinterpret_cast<const float4*>(Hp);
    float4 s3 = make_float4(0.f, 0.f, 0.f, 0.f);
#pragma unroll
    for (int c = 0; c < 16; c++) {
      float hv = hc[(size_t)i * 16 + c];
      float4 g = Hp4[c * 16 + kq];
      s3.x += hv * g.x; s3.y += hv * g.y; s3.z += hv * g.z; s3.w += hv * g.w;
    }
    s.x += s3.x; s.y += s3.y; s.z += s3.z; s.w += s3.w;
  }
  *reinterpret_cast<float4*>(Out + (size_t)i * 64 + kq * 4) = s;
}

__global__ __launch_bounds__(256) void final_out(
    const float* __restrict__ Um, const float* __restrict__ hTV,
    const float* __restrict__ hc, const float* __restrict__ Wm,
    float* __restrict__ out, int n)
{
  __shared__ float sh[1024];
  __shared__ float sW[256];
  for (int q = threadIdx.x; q < 1024; q += 256) sh[q] = hTV[q];
  sW[threadIdx.x] = Wm[threadIdx.x & 255];
  __syncthreads();
  int i = blockIdx.x * 256 + threadIdx.x;
  if (i >= n) return;
  const float* u = Um + (size_t)i * 64;
  float pre[16];
#pragma unroll
  for (int c = 0; c < 16; c++) {
    float s = 0.f;
#pragma unroll
    for (int k = 0; k < 64; k++) s += u[k] * sh[c * 64 + k];
    pre[c] = 0.9f * s + 0.1f * hc[(size_t)i * 16 + c];
  }
#pragma unroll
  for (int j = 0; j < 16; j++) {
    float o = 0.f;
#pragma unroll
    for (int c = 0; c < 16; c++) o += pre[c] * sW[c * 16 + j];
    out[(size_t)i * 16 + j] = o;
  }
}

extern "C" void kernel_launch(void* const* d_in, const int* in_sizes, int n_in,
                              void* d_out, int out_size, void* d_ws, size_t ws_size,
                              hipStream_t stream)
{
  const float* x       = (const float*)d_in[0];
  const int*   eidx    = (const int*)d_in[1];
  const float* ew      = (const float*)d_in[2];
  const float* aw      = (const float*)d_in[3];
  const float* connect = (const float*)d_in[4];
  const float* ci      = (const float*)d_in[5];
  const float* lin1_w  = (const float*)d_in[6];
  const float* lin1_b  = (const float*)d_in[7];
  const float* lin2_w  = (const float*)d_in[8];
  const float* lin2_b  = (const float*)d_in[9];
  const float* lin_a_w = (const float*)d_in[10];
  const float* lin_a_b = (const float*)d_in[11];
  const float* lin_n_w = (const float*)d_in[12];
  const float* lin_n_b = (const float*)d_in[13];
  const float* left_w  = (const float*)d_in[14];
  const float* att_w   = (const float*)d_in[15];
  const float* v_w     = (const float*)d_in[16];
  const float* v_b     = (const float*)d_in[17];
  const float* Wm      = (const float*)d_in[18];
  const float* conf_p  = (const float*)d_in[19];
  const float* b_param = (const float*)d_in[20];
  const int* row = eidx;
  const int* col = eidx + kE;
  float* out = (float*)d_out;

  char* base = (char*)d_ws;
  size_t off = 0;
  auto alloc = [&](size_t bytes) -> void* {
    void* p = base + off;
    off += bytes;
    off = (off + 255) & ~(size_t)255;
    return p;
  };
  float* raw   = (float*)alloc((size_t)kN * kNH * 4);
  float* h16   = (float*)alloc((size_t)kN * kC * 4);
  float* hC    = (float*)alloc((size_t)kN * kC * 4);
  float* nei   = (float*)alloc((size_t)kN * kC * 4);
  float* lx    = (float*)alloc((size_t)kN * kC * 4);
  int*   yhat  = (int*)alloc((size_t)kN * 4);
  float* conf  = (float*)alloc((size_t)kE * 4);
  float* Va    = (float*)alloc((size_t)kN * kK * 4);
  float* Vb    = (float*)alloc((size_t)kN * kK * 4);
  float* Ua    = (float*)alloc((size_t)kN * kK * 4);
  float* Ub    = (float*)alloc((size_t)kN * kK * 4);
  float* T     = (float*)alloc((size_t)kN * kK * 4);
  float* score = (float*)alloc((size_t)kE * 4);
  float* G     = (float*)alloc(64 * 64 * 4);
  float* Gi    = (float*)alloc(64 * 64 * 4);
  float* Gp    = (float*)alloc(64 * 64 * 4);
  float* hTX   = (float*)alloc(kC * kK * 4);
  float* Hp    = (float*)alloc(kC * kK * 4);
  int* hist1   = (int*)alloc(65536 * 4);
  int* h2a     = (int*)alloc(65536 * 4);
  int* h2b     = (int*)alloc(65536 * 4);
  SelState* sel = (SelState*)alloc(sizeof(SelState));
  int* cntR    = (int*)alloc((size_t)kN * 4);
  int* cntC    = (int*)alloc((size_t)kN * 4);
  int* fillR   = (int*)alloc((size_t)kN * 4);
  int* fillC   = (int*)alloc((size_t)kN * 4);
  int* startR  = (int*)alloc((size_t)(kN + 1) * 4);
  int* startC  = (int*)alloc((size_t)(kN + 1) * 4);
  int* eR      = (int*)alloc((size_t)kE * 4);
  int* eC      = (int*)alloc((size_t)kE * 4);
  int* othR    = (int*)alloc((size_t)kE * 4);
  int* othC    = (int*)alloc((size_t)kE * 4);
  float* P     = (float*)alloc((size_t)100 * 5120 * 4);
  const int KpC = 10016, KpX = 512, KpV = 256;
  ushort* BcH = (ushort*)alloc((size_t)256 * KpC * 2);
  ushort* BcL = (ushort*)alloc((size_t)256 * KpC * 2);
  ushort* BxH = (ushort*)alloc((size_t)256 * KpX * 2);
  ushort* BxL = (ushort*)alloc((size_t)256 * KpX * 2);
  ushort* BvH = (ushort*)alloc((size_t)64 * KpV * 2);
  ushort* BvL = (ushort*)alloc((size_t)64 * KpV * 2);
  float* Pbig  = (float*)alloc((size_t)6 * kN * kNH * 4);  // 61 MB split-K partials

  const int eg  = (kE + 255) / 256;
  const int ofg = (kN * 16 + 255) / 256;   // out_fused grid (4 outputs/thread)
  const int gwg = (kN + 3) / 4;

  // ---- pre-split weights ----
  split_bf<<<(256 * KpC + 255) / 256, 256, 0, stream>>>(lin_a_w, BcH, BcL, 256, 10000, KpC);
  split_bf<<<(256 * KpX + 255) / 256, 256, 0, stream>>>(lin1_w, BxH, BxL, 256, 500, KpX);
  split_bf<<<(64 * KpV + 255) / 256, 256, 0, stream>>>(v_w, BvH, BvL, 64, 256, KpV);

  // ---- CSR build (zero span via pointer-diff: alloc pads to 256B) ----
  {
    size_t csrSpan = (size_t)((char*)(fillC + kN) - (char*)cntR);
    (void)hipMemsetAsync(cntR, 0, csrSpan, stream);
  }
  csr_count<<<eg, 256, 0, stream>>>(row, col, cntR, cntC, kE);
  scan2<<<1, 1024, 0, stream>>>(cntR, cntC, startR, startC, kN);
  csr_fill<<<eg, 256, 0, stream>>>(row, col, startR, startC, fillR, fillC, eR, eC, othR, othC, kE);

  // ---- dense front-end ----
  gemm_v3<256, false><<<dim3(157, 1, 6), 256, 0, stream>>>(
      connect, BcH, BcL, nullptr, Pbig, kN, 10000, KpC, 1696, kNH);
  gemm_v3<256, true><<<dim3(157, 1, 1), 256, 0, stream>>>(
      x, BxH, BxL, nullptr, raw, kN, 500, KpX, 512, kNH);
  reduce_raw<<<(kN * kNH / 4 + 255) / 256, 256, 0, stream>>>(
      (const float4*)Pbig, (const float4*)raw, lin_a_b, lin1_b, (float4*)raw);
  h16_argmax<<<(kN * 16 + 255) / 256, 256, 0, stream>>>(raw, lin2_w, lin2_b, h16, yhat, kN);
  (void)hipMemsetAsync(nei, 0, (size_t)kN * kC * 4, stream);
  scatter_nei<<<eg, 256, 0, stream>>>(row, col, aw, yhat, nei, kE);
  norm_xn_h<<<(kN + 255) / 256, 256, 0, stream>>>(nei, h16, lin_n_w, lin_n_b, hC, kN);
  gemm_rowdot<<<(kN * kC + 255) / 256, 256, 0, stream>>>(hC, left_w, nullptr, lx, kN, kC, kC);
  edge_conf<<<eg, 256, 0, stream>>>(row, col, lx, att_w, ci, conf_p, conf, kE);
  gemm_v3<64, true><<<dim3(157, 1, 1), 256, 0, stream>>>(
      raw, BvH, BvL, v_b, Va, kN, 256, KpV, 256, kK);

  float* Ucur = Ua; float* Unxt = Ub;
  float* Vcur = Va; float* Vnxt = Vb;

  // ---- U init: U = spmm(aw,row,V[col]) @ inv(V^T V) ----
  gram2_partial<<<100, 256, 0, stream>>>(Vcur, hC, P, kN, 100);
  gram_reduce2<<<20, 256, 0, stream>>>(P, G, hTX, 100);
  inverse64_spd<<<1, 256, 0, stream>>>(G, Gi, 1.0f, 0.0f, nullptr, nullptr, nullptr);
  spmm_gather<<<gwg, 256, 0, stream>>>(aw, nullptr, nullptr, nullptr, nullptr,
                                       startR, eR, othR, Vcur, T, kN);
  out_fused<<<ofg, 256, 0, stream>>>(T, Gi, nullptr, nullptr, nullptr, nullptr,
                                     Ucur, kN, hist1, h2a, h2b);

  for (int j = 0; j < 4; j++) {
    bool upd_u = ((j & 1) == 0);
    const float* Ma = upd_u ? Ucur : Vcur;   // gathered by row
    const float* Mb = upd_u ? Vcur : Ucur;   // gathered by col
    edge_score<<<eg, 256, 0, stream>>>(ew, row, col, Ma, Mb, score, hist1, kE);
    select_scan<<<1, 1024, 0, stream>>>(hist1, hist1, 1, sel);
    hist_pass2<<<eg, 256, 0, stream>>>(score, sel, h2a, h2b, kE);
    select_scan<<<1, 1024, 0, stream>>>(h2a, h2b, 2, sel);

    const float* Xcur = upd_u ? Ucur : Vcur;
    const float* Moth = upd_u ? Vcur : Ucur;
    float* Xout = upd_u ? Unxt : Vnxt;
    gram2_partial<<<100, 256, 0, stream>>>(Moth, hC, P, kN, 100);
    gram_reduce2<<<20, 256, 0, stream>>>(P, G, hTX, 100);
    inverse64_spd<<<1, 256, 0, stream>>>(G, Gi, 1.1f, 1.0f, hTX, Gp, Hp);
    if (upd_u) spmm_gather<<<gwg, 256, 0, stream>>>(nullptr, score, conf, sel, b_param,
                                                    startR, eR, othR, Vcur, T, kN);
    else       spmm_gather<<<gwg, 256, 0, stream>>>(nullptr, score, conf, sel, b_param,
                                                    startC, eC, othC, Ucur, T, kN);
    out_fused<<<ofg, 256, 0, stream>>>(T, Gi, Xcur, Gp, hC, Hp, Xout, kN, hist1, h2a, h2b);
    if (upd_u) { float* tmp = Ucur; Ucur = Unxt; Unxt = tmp; }
    else       { float* tmp = Vcur; Vcur = Vnxt; Vnxt = tmp; }
  }

  // final: hTV = hC^T @ Vcur (gram2 also writes G; harmless)
  gram2_partial<<<100, 256, 0, stream>>>(Vcur, hC, P, kN, 100);
  gram_reduce2<<<20, 256, 0, stream>>>(P, G, hTX, 100);
  final_out<<<(kN + 255) / 256, 256, 0, stream>>>(Ucur, hTX, hC, Wm, out, kN);
}